// Round 4
// baseline (3425.148 us; speedup 1.0000x reference)
//
#include <hip/hip_runtime.h>
#include <cmath>
#include <cstdint>
#include <cstddef>

#define B_ 8
#define N_ 2048
#define NT 2049
#define NP 2080                /* padded tokens per batch */
#define C_ 512
#define H_ 8
#define HD_ 64
#define L_ 8
#define M_ 128
#define HID_ 2048
#define NC_ 2
#define BNT (B_*NT)            /* 16392 valid rows */
#define RP (B_*NP)             /* 16640 padded rows = 130*128 */
#define SCALE_ 0.125f
#define LN_EPS_ 1e-5f
#define FEAT_EPS_ 1e-6f

#define MODE_GELU  2
#define MODE_RESID 3

typedef unsigned short u16;
typedef unsigned short u16x8 __attribute__((ext_vector_type(8)));
typedef short frag __attribute__((ext_vector_type(8)));
typedef float f32x4 __attribute__((ext_vector_type(4)));

// ---------------- workspace layout ----------------
// floats
constexpr size_t F_X    = 0;                         // RP*512
constexpr size_t F_KVP  = F_X   + (size_t)RP*512;    // 4*64*8192
constexpr size_t F_KSP  = F_KVP + (size_t)4*64*8192;
constexpr size_t F_KV   = F_KSP + (size_t)4*64*128;
constexpr size_t F_KS   = F_KV  + (size_t)64*M_*HD_;
constexpr size_t F_QKVB = F_KS  + (size_t)64*M_;
constexpr size_t F_END  = F_QKVB + 1536;             // 11,183,616 floats
// u16 region
constexpr size_t S_BASE = 2 * F_END;
constexpr size_t S_Y    = S_BASE;                    // [RP][512]  Y; later CTX
constexpr size_t S_V    = S_Y  + (size_t)RP*512;     // [RP][512]  V; HB starts here
constexpr size_t S_KF   = S_V  + (size_t)RP*512;     // [RP][1024] KF
constexpr size_t S_QF   = S_KF + (size_t)RP*1024;    // [RP][1024] QF
constexpr size_t S_WQKV = S_QF + (size_t)RP*1024;    // 1536*512
constexpr size_t S_WO   = S_WQKV + (size_t)1536*512; // 512*512
constexpr size_t S_WF1  = S_WO   + (size_t)512*512;  // 2048*512
constexpr size_t S_WF2  = S_WF1  + (size_t)2048*512; // 512*2048
constexpr size_t S_PT   = S_WF2  + (size_t)512*2048; // 8*128*64
constexpr size_t S_END  = S_PT   + (size_t)8*128*64;
constexpr size_t WS_BYTES = S_END * 2;               // 153,393,152

// ---------------- helpers ----------------
__device__ __forceinline__ float wave_reduce(float v) {
#pragma unroll
  for (int off = 32; off > 0; off >>= 1) v += __shfl_down(v, off, 64);
  return v;
}
__device__ __forceinline__ float b2f(u16 u) {
  union { float f; uint32_t i; } v; v.i = ((uint32_t)u) << 16; return v.f;
}
__device__ __forceinline__ u16 f2b(float f) {
  union { float f; uint32_t i; } v; v.f = f;
  uint32_t r = v.i + 0x7FFF + ((v.i >> 16) & 1);
  return (u16)(r >> 16);
}
__device__ __forceinline__ void gstage(const u16* g, u16* lds_base, int lane) {
#if __has_builtin(__builtin_amdgcn_global_load_lds)
  __builtin_amdgcn_global_load_lds((const __attribute__((address_space(1))) void*)g,
      (__attribute__((address_space(3))) void*)lds_base, 16, 0, 0);
#else
  *(u16x8*)(lds_base + lane * 8) = *(const u16x8*)g;
#endif
}
// XCD-aware bijective block swizzle (T1): contiguous work chunk per XCD.
// Requires nwg % 8 == 0 (all call sites satisfy; guarded anyway).
__device__ __forceinline__ void xcd_swz(int& bx, int& by) {
  int gx = gridDim.x;
  int nwg = gx * gridDim.y;
  int hw = blockIdx.x + blockIdx.y * gx;
  if (nwg & 7) { bx = blockIdx.x; by = blockIdx.y; return; }
  int cpx = nwg >> 3;
  int swz = (hw & 7) * cpx + (hw >> 3);
  bx = swz % gx; by = swz / gx;
}

// ---------------- embedding ----------------
__global__ __launch_bounds__(256) void embed_k(const int* __restrict__ ids,
    const float* __restrict__ tok, const float* __restrict__ cls,
    const float* __restrict__ pos, float* __restrict__ X) {
  int row = blockIdx.x;
  int b = row / NT, n = row - b * NT;
  int t = threadIdx.x;
  const float* src = (n == 0) ? cls : tok + (size_t)ids[b * N_ + n - 1] * C_;
  size_t rp = (size_t)b * NP + n;
  X[rp * C_ + t]       = src[t]       + pos[(size_t)n * C_ + t];
  X[rp * C_ + t + 256] = src[t + 256] + pos[(size_t)n * C_ + t + 256];
}

// ---------------- weight transpose + convert + PT + qkv bias (per layer) ----------------
__global__ __launch_bounds__(256) void wconv_k(
    const float* __restrict__ qW, const float* __restrict__ kW,
    const float* __restrict__ vW, const float* __restrict__ oW,
    const float* __restrict__ f1W, const float* __restrict__ f2W,
    const float* __restrict__ projL,
    const float* __restrict__ qb, const float* __restrict__ kb,
    const float* __restrict__ vb,
    u16* __restrict__ Wqkv, u16* __restrict__ Wo,
    u16* __restrict__ Wf1, u16* __restrict__ Wf2,
    u16* __restrict__ PT, float* __restrict__ QKVB) {
  __shared__ float tile[32][33];
  int bid = blockIdx.x, t = threadIdx.x;
  if (bid >= 3104) {            // qkv bias concat
    int i = (bid - 3104) * 256 + t;
    QKVB[i] = (i < 512) ? qb[i] : (i < 1024) ? kb[i - 512] : vb[i - 1024];
    return;
  }
  if (bid >= 3072) {            // PT[h][m][d] = proj[h][d][m]
    int base = (bid - 3072) * 2048 + t * 8;
#pragma unroll
    for (int j = 0; j < 8; ++j) {
      int idx = base + j;
      int h = idx >> 13, rem = idx & 8191, m = rem >> 6, d = rem & 63;
      PT[idx] = f2b(projL[(size_t)h * 8192 + d * 128 + m]);
    }
    return;
  }
  int ti = t >> 5, tj = t & 31;
  const float* src; u16* dst; int k0, n0, ldn, ldk, scol;
  if (bid < 768) {
    int tk = bid & 15, tn = bid >> 4;
    k0 = tk * 32; n0 = tn * 32;
    int sel = n0 >> 9; scol = n0 & 511;
    src = (sel == 0) ? qW : (sel == 1) ? kW : vW;
    ldn = 512; dst = Wqkv; ldk = 512;
  } else if (bid < 1024) {
    int b2 = bid - 768;
    int tk = b2 & 15, tn = b2 >> 4;
    k0 = tk * 32; n0 = tn * 32; scol = n0;
    src = oW; ldn = 512; dst = Wo; ldk = 512;
  } else if (bid < 2048) {
    int b2 = bid - 1024;
    int tk = b2 & 15, tn = b2 >> 4;
    k0 = tk * 32; n0 = tn * 32; scol = n0;
    src = f1W; ldn = 2048; dst = Wf1; ldk = 512;
  } else {
    int b2 = bid - 2048;
    int tk = b2 & 63, tn = b2 >> 6;
    k0 = tk * 32; n0 = tn * 32; scol = n0;
    src = f2W; ldn = 512; dst = Wf2; ldk = 2048;
  }
  const float* sp = src + (size_t)k0 * ldn + scol;
  u16* dp = dst + (size_t)n0 * ldk + k0;
#pragma unroll
  for (int p = 0; p < 4; ++p)
    tile[ti + p * 8][tj] = sp[(size_t)(ti + p * 8) * ldn + tj];
  __syncthreads();
#pragma unroll
  for (int p = 0; p < 4; ++p)
    dp[(size_t)(ti + p * 8) * ldk + tj] = f2b(tile[tj][ti + p * 8]);
}

// ---------------- LayerNorm -> bf16 ----------------
__global__ __launch_bounds__(256) void ln_bf_k(const float* __restrict__ X,
    const float* __restrict__ g, const float* __restrict__ b,
    u16* __restrict__ Y) {
  int w = threadIdx.x >> 6, lane = threadIdx.x & 63;
  int row = blockIdx.x * 4 + w;
  const float* xr = X + (size_t)row * C_;
  float v[8];
  *(float4*)&v[0] = *(const float4*)(xr + lane * 8);
  *(float4*)&v[4] = *(const float4*)(xr + lane * 8 + 4);
  float s = 0.f;
#pragma unroll
  for (int j = 0; j < 8; ++j) s += v[j];
  s = wave_reduce(s);
  float mu = __shfl(s, 0, 64) * (1.0f / C_);
  float sq = 0.f;
#pragma unroll
  for (int j = 0; j < 8; ++j) { float d = v[j] - mu; sq = fmaf(d, d, sq); }
  sq = wave_reduce(sq);
  float rs = rsqrtf(__shfl(sq, 0, 64) * (1.0f / C_) + LN_EPS_);
  float gv[8], bv[8];
  *(float4*)&gv[0] = *(const float4*)(g + lane * 8);
  *(float4*)&gv[4] = *(const float4*)(g + lane * 8 + 4);
  *(float4*)&bv[0] = *(const float4*)(b + lane * 8);
  *(float4*)&bv[4] = *(const float4*)(b + lane * 8 + 4);
  u16x8 o;
#pragma unroll
  for (int j = 0; j < 8; ++j) o[j] = f2b((v[j] - mu) * rs * gv[j] + bv[j]);
  *(u16x8*)(Y + (size_t)row * C_ + lane * 8) = o;
}

// ---------------- 256x256 8-wave phased GEMM (fc1) ----------------
// T3+T4+T5 structure (guide §5 template, adapted): BM=BN=256, BK=64, 512 thr
// (2Mx4N waves, each owns 128x64). Per K-tile: 4 phases, each {stage one
// half-tile of kt+1 || 4-8 ds_read_b128 || 16 MFMA (setprio-wrapped)},
// double-barrier rhythm. Counted vmcnt(2) once per K-tile (never 0 in
// steady state). LDS 128KB dbuf; same (lc^lr)/(^sx) both-sides swizzle.
__global__ __launch_bounds__(512, 2) void gemm256_k(
    const u16* __restrict__ A, int lda,
    const u16* __restrict__ Wt,
    const float* __restrict__ bias,
    float* __restrict__ outF, u16* __restrict__ outB,
    int ldc, int Kdim, int mode) {
  __shared__ __align__(16) u16 As[2][2][128 * 64];   // [buf][half][...]
  __shared__ __align__(16) u16 Bs[2][2][128 * 64];
  const int t = threadIdx.x, w = t >> 6, l = t & 63;
  int bx, by; xcd_swz(bx, by);
  const int row0 = by * 256, col0 = bx * 256;
  const int wm = w >> 2, wn = w & 3;          // 2 x 4 wave grid
  const int lm = l & 15, lkb = l >> 4;
  const int lr = l >> 3, lc = l & 7;
  const int kch = (lc ^ lr) * 8;
  const int sx = lm & 7;
  const int bcl = (wn & 1) * 64;              // local col base in B-half
  const u16* Ag = A  + (size_t)(row0 + lr) * lda  + kch;
  const u16* Bg = Wt + (size_t)(col0 + lr) * Kdim + kch;
  f32x4 acc[8][4] = {};
  const int nk = Kdim >> 6;

#define STAGE_A(kt_, h_, b_) do {                                            \
    _Pragma("unroll")                                                        \
    for (int q = 0; q < 2; ++q) {                                            \
      int rg = w * 2 + q;                                                    \
      gstage(Ag + (size_t)((h_) * 128 + rg * 8) * lda + (kt_) * 64,          \
             &As[b_][h_][rg * 512], l);                                      \
    } } while (0)
#define STAGE_B(kt_, h_, b_) do {                                            \
    _Pragma("unroll")                                                        \
    for (int q = 0; q < 2; ++q) {                                            \
      int rg = w * 2 + q;                                                    \
      gstage(Bg + (size_t)((h_) * 128 + rg * 8) * Kdim + (kt_) * 64,         \
             &Bs[b_][h_][rg * 512], l);                                      \
    } } while (0)
#define RD_A(Ah_, rh_, ks_, dst_) do {                                       \
    _Pragma("unroll")                                                        \
    for (int i_ = 0; i_ < 4; ++i_)                                           \
      dst_[i_] = *(const frag*)&(Ah_)[((rh_) * 64 + i_ * 16 + lm) * 64 +     \
                                      ((((ks_) * 4 + lkb) ^ sx) * 8)];       \
    } while (0)
#define RD_B(Bh_, ks_, dst_) do {                                            \
    _Pragma("unroll")                                                        \
    for (int j_ = 0; j_ < 4; ++j_)                                           \
      dst_[j_] = *(const frag*)&(Bh_)[(bcl + j_ * 16 + lm) * 64 +            \
                                      ((((ks_) * 4 + lkb) ^ sx) * 8)];       \
    } while (0)
#define MFMA16(rbase_, af_, bf_) do {                                        \
    _Pragma("unroll")                                                        \
    for (int i_ = 0; i_ < 4; ++i_)                                           \
      _Pragma("unroll")                                                      \
      for (int j_ = 0; j_ < 4; ++j_)                                         \
        acc[(rbase_) + i_][j_] = __builtin_amdgcn_mfma_f32_16x16x32_bf16(    \
            af_[i_], bf_[j_], acc[(rbase_) + i_][j_], 0, 0, 0);              \
    } while (0)

  // prologue: stage tile 0 fully into buf 0 (8 loads/thread-pair pattern)
  STAGE_A(0, 0, 0); STAGE_A(0, 1, 0); STAGE_B(0, 0, 0); STAGE_B(0, 1, 0);

  for (int kt = 0; kt < nk; ++kt) {
    const int pb = kt & 1;
    const bool more = (kt + 1 < nk);
    const u16* Ah = &As[pb][wm][0];
    const u16* Bh = &Bs[pb][wn >> 1][0];
    frag af0[4], af1[4], bf0[4], bf1[4];
    // ---- PH0: ensure tile kt landed; rows 0-63, ks=0 ----
    if (more) {
      STAGE_A(kt + 1, 0, pb ^ 1);
      asm volatile("s_waitcnt vmcnt(2)" ::: "memory");   // kt's 8 landed; 2 in flight
    } else {
      asm volatile("s_waitcnt vmcnt(0)" ::: "memory");
    }
    __builtin_amdgcn_s_barrier();
    __builtin_amdgcn_sched_barrier(0);
    RD_A(Ah, 0, 0, af0);
    RD_B(Bh, 0, bf0);
    __builtin_amdgcn_s_setprio(1);
    MFMA16(0, af0, bf0);
    __builtin_amdgcn_s_setprio(0);
    __builtin_amdgcn_sched_barrier(0);
    __builtin_amdgcn_s_barrier();
    // ---- PH1: rows 64-127, ks=0 (reuse bf0) ----
    if (more) STAGE_A(kt + 1, 1, pb ^ 1);
    RD_A(Ah, 1, 0, af1);
    __builtin_amdgcn_s_setprio(1);
    MFMA16(4, af1, bf0);
    __builtin_amdgcn_s_setprio(0);
    __builtin_amdgcn_sched_barrier(0);
    __builtin_amdgcn_s_barrier();
    // ---- PH2: rows 0-63, ks=1 ----
    if (more) STAGE_B(kt + 1, 0, pb ^ 1);
    RD_A(Ah, 0, 1, af0);
    RD_B(Bh, 1, bf1);
    __builtin_amdgcn_s_setprio(1);
    MFMA16(0, af0, bf1);
    __builtin_amdgcn_s_setprio(0);
    __builtin_amdgcn_sched_barrier(0);
    __builtin_amdgcn_s_barrier();
    // ---- PH3: rows 64-127, ks=1 ----
    if (more) STAGE_B(kt + 1, 1, pb ^ 1);
    RD_A(Ah, 1, 1, af1);
    __builtin_amdgcn_s_setprio(1);
    MFMA16(4, af1, bf1);
    __builtin_amdgcn_s_setprio(0);
    __builtin_amdgcn_sched_barrier(0);
    __builtin_amdgcn_s_barrier();   // all waves done with buf pb before restage
  }
#undef STAGE_A
#undef STAGE_B
#undef RD_A
#undef RD_B
#undef MFMA16

#pragma unroll
  for (int rf = 0; rf < 8; ++rf) {
#pragma unroll
    for (int r = 0; r < 4; ++r) {
      int grow = row0 + wm * 128 + rf * 16 + lkb * 4 + r;
      if (mode == MODE_RESID) {
        float* orow = outF + (size_t)grow * ldc + col0;
#pragma unroll
        for (int cf = 0; cf < 4; ++cf) {
          int gc = wn * 64 + cf * 16 + lm;
          orow[gc] += acc[rf][cf][r] + bias[col0 + gc];
        }
      } else { // MODE_GELU (fast sigmoid form)
        u16* orow = outB + (size_t)grow * ldc + col0;
#pragma unroll
        for (int cf = 0; cf < 4; ++cf) {
          int gc = wn * 64 + cf * 16 + lm;
          float v = acc[rf][cf][r] + bias[col0 + gc];
          float u = v * (1.5957691216f + 0.0713548162f * v * v);
          v = v / (1.f + __expf(-u));
          orow[gc] = f2b(v);
        }
      }
    }
  }
}

// ---------------- bf16 MFMA GEMM, BM=64 variant (o-proj / fc2), 2-phase dbuf
__global__ __launch_bounds__(256) void gemm_bf64_k(
    const u16* __restrict__ A, int lda,
    const u16* __restrict__ Wt,
    const float* __restrict__ bias,
    float* __restrict__ outF, u16* __restrict__ outB,
    int ldc, int Kdim, int mode) {
  __shared__ __align__(16) u16 As[2][64 * 64];
  __shared__ __align__(16) u16 Bs[2][128 * 64];
  const int t = threadIdx.x, w = t >> 6, l = t & 63;
  int bx, by; xcd_swz(bx, by);
  const int row0 = by * 64, col0 = bx * 128;
  const int wm = w & 1, wn = w >> 1;          // wave: 32 rows x 64 cols
  const int lm = l & 15, lkb = l >> 4;
  const int lr = l >> 3, lc = l & 7;
  const int kch = (lc ^ lr) * 8;
  const u16* Ag = A  + (size_t)(row0 + lr) * lda  + kch;
  const u16* Bg = Wt + (size_t)(col0 + lr) * Kdim + kch;
  const int sx = lm & 7;
  f32x4 acc[2][4] = {};
  const int nk = Kdim >> 6;
  // prologue: stage tile 0 -> buffer 0 (6 loads/wave: 2 A + 4 B)
#pragma unroll
  for (int q = 0; q < 2; ++q) {
    int c8 = w * 2 + q;
    gstage(Ag + (size_t)c8 * 8 * lda, &As[0][c8 * 512], l);
  }
#pragma unroll
  for (int q = 0; q < 4; ++q) {
    int c8 = w * 4 + q;
    gstage(Bg + (size_t)c8 * 8 * Kdim, &Bs[0][c8 * 512], l);
  }
  for (int kt = 0; kt < nk; ++kt) {
    const int cur = kt & 1;
    if (kt + 1 < nk) {
      const int k0 = (kt + 1) << 6;
#pragma unroll
      for (int q = 0; q < 2; ++q) {
        int c8 = w * 2 + q;
        gstage(Ag + (size_t)c8 * 8 * lda + k0, &As[cur ^ 1][c8 * 512], l);
      }
#pragma unroll
      for (int q = 0; q < 4; ++q) {
        int c8 = w * 4 + q;
        gstage(Bg + (size_t)c8 * 8 * Kdim + k0, &Bs[cur ^ 1][c8 * 512], l);
      }
      asm volatile("s_waitcnt vmcnt(6)" ::: "memory");
    } else {
      asm volatile("s_waitcnt vmcnt(0)" ::: "memory");
    }
    __builtin_amdgcn_s_barrier();
    __builtin_amdgcn_sched_barrier(0);
#pragma unroll
    for (int ks = 0; ks < 2; ++ks) {
      frag af[2], bf4[4];
#pragma unroll
      for (int i = 0; i < 2; ++i)
        af[i] = *(const frag*)&As[cur][(wm * 32 + i * 16 + lm) * 64 + (((ks * 4 + lkb) ^ sx) * 8)];
#pragma unroll
      for (int j = 0; j < 4; ++j)
        bf4[j] = *(const frag*)&Bs[cur][(wn * 64 + j * 16 + lm) * 64 + (((ks * 4 + lkb) ^ sx) * 8)];
#pragma unroll
      for (int i = 0; i < 2; ++i)
#pragma unroll
        for (int j = 0; j < 4; ++j)
          acc[i][j] = __builtin_amdgcn_mfma_f32_16x16x32_bf16(af[i], bf4[j], acc[i][j], 0, 0, 0);
    }
    __builtin_amdgcn_sched_barrier(0);
    __builtin_amdgcn_s_barrier();
  }
#pragma unroll
  for (int i = 0; i < 2; ++i) {
#pragma unroll
    for (int r = 0; r < 4; ++r) {
      int grow = row0 + wm * 32 + i * 16 + lkb * 4 + r;
      if (mode == MODE_RESID) {
        float* orow = outF + (size_t)grow * ldc + col0;
#pragma unroll
        for (int j = 0; j < 4; ++j) {
          int gc = wn * 64 + j * 16 + lm;
          orow[gc] += acc[i][j][r] + bias[col0 + gc];
        }
      } else { // MODE_GELU (fast sigmoid form)
        u16* orow = outB + (size_t)grow * ldc + col0;
#pragma unroll
        for (int j = 0; j < 4; ++j) {
          int gc = wn * 64 + j * 16 + lm;
          float v = acc[i][j][r] + bias[col0 + gc];
          float u = v * (1.5957691216f + 0.0713548162f * v * v);
          v = v / (1.f + __expf(-u));
          orow[gc] = f2b(v);
        }
      }
    }
  }
}

// ---------------- fused QKV GEMM + feature map ----------------
// grid (12, 130) swizzled. col-blocks 0..3: q-heads, 4..7: k-heads, 8..11: v.
__global__ __launch_bounds__(256) void gemmqkv_k(
    const u16* __restrict__ A,
    const u16* __restrict__ Wt,          // Wqkv [1536][512]
    const float* __restrict__ bias,      // [1536]
    u16* __restrict__ Vout,              // [RP][512]
    u16* __restrict__ QF, u16* __restrict__ KF,   // [RP][1024]
    const u16* __restrict__ PT,          // [8][128][64]
    const int* __restrict__ attn) {
  __shared__ __align__(16) u16 As[128 * 64];   // later: qtile head0
  __shared__ __align__(16) u16 Bs[128 * 64];   // later: qtile head1
  __shared__ __align__(16) u16 ptb[128 * 64];  // PT[h] staged, swizzled
  __shared__ float sxe[128][2];
  const int t = threadIdx.x, w = t >> 6, l = t & 63;
  int bx, by; xcd_swz(bx, by);
  const int cx = bx;
  const int row0 = by * 128, col0 = cx * 128;
  const int wm = w & 1, wn = w >> 1;
  const int lm = l & 15, lkb = l >> 4;
  const int lr = l >> 3, lc = l & 7;
  const int kch = (lc ^ lr) * 8;
  const u16* Ag = A  + (size_t)(row0 + lr) * 512 + kch;
  const u16* Bg = Wt + (size_t)(col0 + lr) * 512 + kch;
  const int sx = lm & 7;
  f32x4 acc[4][4] = {};
  for (int k0 = 0; k0 < 512; k0 += 64) {
    __syncthreads();
#pragma unroll
    for (int j = 0; j < 4; ++j) {
      int c8 = w * 4 + j;
      gstage(Ag + (size_t)c8 * 8 * 512 + k0, &As[c8 * 512], l);
      gstage(Bg + (size_t)c8 * 8 * 512 + k0, &Bs[c8 * 512], l);
    }
    __syncthreads();
#pragma unroll
    for (int ks = 0; ks < 2; ++ks) {
      frag af[4], bf4[4];
#pragma unroll
      for (int i = 0; i < 4; ++i)
        af[i] = *(const frag*)&As[(wm * 64 + i * 16 + lm) * 64 + (((ks * 4 + lkb) ^ sx) * 8)];
#pragma unroll
      for (int j = 0; j < 4; ++j)
        bf4[j] = *(const frag*)&Bs[(wn * 64 + j * 16 + lm) * 64 + (((ks * 4 + lkb) ^ sx) * 8)];
#pragma unroll
      for (int i = 0; i < 4; ++i)
#pragma unroll
        for (int j = 0; j < 4; ++j)
          acc[i][j] = __builtin_amdgcn_mfma_f32_16x16x32_bf16(af[i], bf4[j], acc[i][j], 0, 0, 0);
    }
  }
  // ---- V path ----
  if (cx >= 8) {
    int c0v = col0 - 1024;
#pragma unroll
    for (int i = 0; i < 4; ++i) {
#pragma unroll
      for (int r = 0; r < 4; ++r) {
        int grow = row0 + wm * 64 + i * 16 + lkb * 4 + r;
        int bb = grow / NP, nn = grow - bb * NP;
        float mrow = (nn == 0) ? 1.f : ((nn < NT) ? (float)attn[bb * N_ + nn - 1] : 0.f);
        u16* orow = Vout + (size_t)grow * 512 + c0v;
#pragma unroll
        for (int j = 0; j < 4; ++j) {
          int gc = wn * 64 + j * 16 + lm;
          orow[gc] = f2b((acc[i][j][r] + bias[col0 + gc]) * mrow);
        }
      }
    }
    return;
  }
  // ---- Q/K path: write scaled/masked tile to LDS (swizzled, per-head) ----
  const bool isq = (cx < 4);
  const int hbase = (isq ? cx : cx - 4) * 2;
  __syncthreads();            // all waves done reading As/Bs
  {
    u16* qt = wn ? Bs : As;
#pragma unroll
    for (int i = 0; i < 4; ++i) {
#pragma unroll
      for (int r = 0; r < 4; ++r) {
        int rl = wm * 64 + i * 16 + lkb * 4 + r;
        float mrow;
        if (isq) mrow = SCALE_;
        else {
          int grow = row0 + rl;
          int bb = grow / NP, nn = grow - bb * NP;
          mrow = (nn == 0) ? 1.f : ((nn < NT) ? (float)attn[bb * N_ + nn - 1] : 0.f);
        }
#pragma unroll
        for (int j = 0; j < 4; ++j) {
          int gcc = j * 16 + lm;
          float v = (acc[i][j][r] + bias[col0 + wn * 64 + gcc]) * mrow;
          qt[rl * 64 + (((gcc >> 3) ^ (rl & 7)) * 8) + (gcc & 7)] = f2b(v);
        }
      }
    }
  }
  // stage PT for head hbase+0 (independent of qtile)
  {
    const u16* Pg = PT + (size_t)hbase * 8192 + (size_t)lr * 64 + kch;
#pragma unroll
    for (int q = 0; q < 4; ++q) {
      int c8 = w * 4 + q;
      gstage(Pg + (size_t)c8 * 8 * 64, &ptb[c8 * 512], l);
    }
  }
  __syncthreads();
  // ---- 0.5*||x||^2 per (row, head) ----
  {
    int rowi = t >> 1, hf = t & 1;
    const u16* qq = hf ? Bs : As;
    float s = 0.f;
#pragma unroll
    for (int c = 0; c < 8; ++c) {
      const u16* p = &qq[rowi * 64 + ((c ^ (rowi & 7)) * 8)];
#pragma unroll
      for (int e = 0; e < 8; ++e) { float a = b2f(p[e]); s = fmaf(a, a, s); }
    }
    sxe[rowi][hf] = 0.5f * s;
  }
  __syncthreads();
  // ---- feature MFMA per head ----
  u16* OF = isq ? QF : KF;
#pragma unroll
  for (int hp = 0; hp < 2; ++hp) {
    if (hp == 1) {
      __syncthreads();
      const u16* Pg = PT + (size_t)(hbase + 1) * 8192 + (size_t)lr * 64 + kch;
#pragma unroll
      for (int q = 0; q < 4; ++q) {
        int c8 = w * 4 + q;
        gstage(Pg + (size_t)c8 * 8 * 64, &ptb[c8 * 512], l);
      }
      __syncthreads();
    }
    const u16* qt = hp ? Bs : As;
    f32x4 a2[2][8] = {};
#pragma unroll
    for (int ks = 0; ks < 2; ++ks) {
      frag af2[2], bf2[8];
#pragma unroll
      for (int i = 0; i < 2; ++i)
        af2[i] = *(const frag*)&qt[(w * 32 + i * 16 + lm) * 64 + (((ks * 4 + lkb) ^ sx) * 8)];
#pragma unroll
      for (int j = 0; j < 8; ++j)
        bf2[j] = *(const frag*)&ptb[(j * 16 + lm) * 64 + (((ks * 4 + lkb) ^ sx) * 8)];
#pragma unroll
      for (int i = 0; i < 2; ++i)
#pragma unroll
        for (int j = 0; j < 8; ++j)
          a2[i][j] = __builtin_amdgcn_mfma_f32_16x16x32_bf16(af2[i], bf2[j], a2[i][j], 0, 0, 0);
    }
    int hg = hbase + hp;
#pragma unroll
    for (int i = 0; i < 2; ++i) {
#pragma unroll
      for (int r = 0; r < 4; ++r) {
        int R = w * 32 + i * 16 + lkb * 4 + r;
        int grow = row0 + R;
        int bb = grow / NP, nn = grow - bb * NP;
        bool valid = nn < NT;
        float xs = sxe[R][hp];
        u16* orow = OF + (size_t)grow * 1024 + (size_t)hg * 128;
#pragma unroll
        for (int j = 0; j < 8; ++j) {
          int m = j * 16 + lm;
          float v = valid ? (__expf(a2[i][j][r] - xs) + FEAT_EPS_) : 0.f;
          orow[m] = f2b(v);
        }
      }
    }
  }
}

// ---------------- kv partial (pure accumulation, fp32) ----------------
// Vectorized staging (u16x8) + register prefetch of next tile: this kernel
// runs at 1 block/CU (grid 4x64) so TLP can't hide load latency — prefetch
// under the 8-tok FMA phase does.
__global__ __launch_bounds__(256) void kvpart_k(const u16* __restrict__ KF,
    const u16* __restrict__ Vb, float* __restrict__ KVP,
    float* __restrict__ KSP) {
  int ci = blockIdx.x, bh = blockIdx.y;
  int b = bh >> 3, h = bh & 7;
  size_t rb0 = (size_t)b * NP + ci * 520;
  __shared__ __align__(16) float kfs[8 * 132];
  __shared__ __align__(16) float vsm[8 * 68];
  int t = threadIdx.x;
  const int d0 = (t & 7) * 8, m0 = (t >> 3) * 4;
  // staging roles: t<128 loads KF (8 tok x 16 groups of 8 m);
  // t in [128,192) loads V (8 tok x 8 groups of 8 d).
  const bool hk = t < 128;
  const bool hv = (t >= 128) && (t < 192);
  const int ktok = t >> 4, kmj = (t & 15) * 8;
  const int vtok = (t - 128) >> 3, vdj = (t & 7) * 8;
  float acc[4][8] = {};
  float ks[4] = {};
  u16x8 rk, rv;
  if (hk) rk = *(const u16x8*)&KF[(rb0 + ktok) * 1024 + h * 128 + kmj];
  if (hv) rv = *(const u16x8*)&Vb[(rb0 + vtok) * 512 + h * 64 + vdj];
  for (int tile = 0; tile < 65; ++tile) {
    if (hk) {
#pragma unroll
      for (int e = 0; e < 8; ++e) kfs[ktok * 132 + kmj + e] = b2f(rk[e]);
    }
    if (hv) {
#pragma unroll
      for (int e = 0; e < 8; ++e) vsm[vtok * 68 + vdj + e] = b2f(rv[e]);
    }
    __syncthreads();
    if (tile + 1 < 65) {       // prefetch next tile into registers
      size_t rb = rb0 + (size_t)(tile + 1) * 8;
      if (hk) rk = *(const u16x8*)&KF[(rb + ktok) * 1024 + h * 128 + kmj];
      if (hv) rv = *(const u16x8*)&Vb[(rb + vtok) * 512 + h * 64 + vdj];
    }
#pragma unroll
    for (int tok = 0; tok < 8; ++tok) {
      float kq[4], va[8];
      *(float4*)&kq[0] = *(const float4*)&kfs[tok * 132 + m0];
      *(float4*)&va[0] = *(const float4*)&vsm[tok * 68 + d0];
      *(float4*)&va[4] = *(const float4*)&vsm[tok * 68 + d0 + 4];
#pragma unroll
      for (int mi = 0; mi < 4; ++mi)
#pragma unroll
        for (int di = 0; di < 8; ++di)
          acc[mi][di] = fmaf(kq[mi], va[di], acc[mi][di]);
      if ((t & 7) == 0) { ks[0] += kq[0]; ks[1] += kq[1]; ks[2] += kq[2]; ks[3] += kq[3]; }
    }
    __syncthreads();
  }
  size_t base = ((size_t)ci * 64 + bh) * 8192;
#pragma unroll
  for (int mi = 0; mi < 4; ++mi)
#pragma unroll
    for (int di = 0; di < 8; ++di)
      KVP[base + (size_t)(m0 + mi) * 64 + d0 + di] = acc[mi][di];
  if ((t & 7) == 0) {
#pragma unroll
    for (int mi = 0; mi < 4; ++mi)
      KSP[((size_t)ci * 64 + bh) * 128 + m0 + mi] = ks[mi];
  }
}

__global__ __launch_bounds__(256) void kvred_k(const float* __restrict__ KVP,
    const float* __restrict__ KSP, float* __restrict__ KV,
    float* __restrict__ KSUM) {
  int bh = blockIdx.x, t = threadIdx.x;
#pragma unroll
  for (int p = 0; p < 32; ++p) {
    int e = p * 256 + t;
    float s = 0.f;
#pragma unroll
    for (int ci = 0; ci < 4; ++ci) s += KVP[((size_t)ci * 64 + bh) * 8192 + e];
    KV[(size_t)bh * 8192 + e] = s;
  }
  if (t < 128) {
    float s = 0.f;
#pragma unroll
    for (int ci = 0; ci < 4; ++ci) s += KSP[((size_t)ci * 64 + bh) * 128 + t];
    KSUM[(size_t)bh * 128 + t] = s;
  }
}

// ---------------- ctx: (qf @ kv) / max(qf . ksum, 1e-6) ----------------
__global__ __launch_bounds__(256) void ctx_k(const u16* __restrict__ QF,
    const float* __restrict__ KVg, const float* __restrict__ KSUM,
    u16* __restrict__ CTXo) {
  __shared__ float qfs[128 * 36];
  __shared__ float kvs[128 * 68];
  __shared__ float ksums[128];
  __shared__ float dls[32];
  __shared__ float dpart[8 * 32];
  int t = threadIdx.x;
  int bx, by; xcd_swz(bx, by);
  int bh = by; int b = bh >> 3, h = bh & 7;
  int n0 = bx * 32;
  size_t rbase = (size_t)b * NP + n0;
#pragma unroll
  for (int p = 0; p < 16; ++p) {
    int e = p * 256 + t; int m = e & 127; int tok = e >> 7;
    qfs[m * 36 + tok] = b2f(QF[(rbase + tok) * 1024 + h * 128 + m]);
  }
#pragma unroll
  for (int p = 0; p < 32; ++p) {
    int e = p * 256 + t;
    kvs[(e >> 6) * 68 + (e & 63)] = KVg[(size_t)bh * 8192 + e];
  }
  if (t < 128) ksums[t] = KSUM[bh * 128 + t];
  __syncthreads();
  {
    int j = t & 31, pp = t >> 5;
    float s = 0.f;
#pragma unroll
    for (int mi = 0; mi < 16; ++mi) {
      int m = pp * 16 + mi;
      s = fmaf(qfs[m * 36 + j], ksums[m], s);
    }
    dpart[pp * 32 + j] = s;
  }
  __syncthreads();
  if (t < 32) {
    float den = 0.f;
#pragma unroll
    for (int pp = 0; pp < 8; ++pp) den += dpart[pp * 32 + t];
    dls[t] = 1.f / fmaxf(den, 1e-6f);
  }
  __syncthreads();
  {
    const int d0 = (t & 15) * 4, tok0 = (t >> 4) * 2;
    float acc[2][4] = {};
#pragma unroll 16
    for (int m = 0; m < 128; ++m) {
      float q0 = qfs[m * 36 + tok0];
      float q1 = qfs[m * 36 + tok0 + 1];
      float4 kv4 = *(const float4*)&kvs[m * 68 + d0];
      acc[0][0] = fmaf(q0, kv4.x, acc[0][0]); acc[0][1] = fmaf(q0, kv4.y, acc[0][1]);
      acc[0][2] = fmaf(q0, kv4.z, acc[0][2]); acc[0][3] = fmaf(q0, kv4.w, acc[0][3]);
      acc[1][0] = fmaf(q1, kv4.x, acc[1][0]); acc[1][1] = fmaf(q1, kv4.y, acc[1][1]);
      acc[1][2] = fmaf(q1, kv4.z, acc[1][2]); acc[1][3] = fmaf(q1, kv4.w, acc[1][3]);
    }
#pragma unroll
    for (int r = 0; r < 2; ++r) {
      int n = n0 + tok0 + r;
      if (n >= NT) continue;
      float rd = dls[tok0 + r];
      u16* o = CTXo + (rbase + tok0 + r) * C_ + h * HD_ + d0;
#pragma unroll
      for (int c = 0; c < 4; ++c) o[c] = f2b(acc[r][c] * rd);
    }
  }
}

// ---------------- final: LN(x[b,0]) @ headW + headb ----------------
__global__ __launch_bounds__(256) void final_k(const float* __restrict__ X,
    const float* __restrict__ g, const float* __restrict__ beta,
    const float* __restrict__ hW, const float* __restrict__ hb,
    float* __restrict__ out) {
  int b = blockIdx.x, t = threadIdx.x;
  const float* xr = X + (size_t)b * NP * C_;
  float v0 = xr[t], v1 = xr[t + 256];
  __shared__ float red[4][4];
  float s = wave_reduce(v0 + v1);
  if ((t & 63) == 0) red[0][t >> 6] = s;
  __syncthreads();
  float mu = (red[0][0] + red[0][1] + red[0][2] + red[0][3]) * (1.0f / C_);
  float d0 = v0 - mu, d1 = v1 - mu;
  float s2 = wave_reduce(d0 * d0 + d1 * d1);
  if ((t & 63) == 0) red[1][t >> 6] = s2;
  __syncthreads();
  float var = (red[1][0] + red[1][1] + red[1][2] + red[1][3]) * (1.0f / C_);
  float rs = rsqrtf(var + LN_EPS_);
  float n0 = d0 * rs * g[t] + beta[t];
  float n1 = d1 * rs * g[t + 256] + beta[t + 256];
  float p0 = n0 * hW[t * NC_]     + n1 * hW[(t + 256) * NC_];
  float p1 = n0 * hW[t * NC_ + 1] + n1 * hW[(t + 256) * NC_ + 1];
  float t0 = wave_reduce(p0);
  float t1 = wave_reduce(p1);
  if ((t & 63) == 0) { red[2][t >> 6] = t0; red[3][t >> 6] = t1; }
  __syncthreads();
  if (t == 0) {
    out[b * NC_]     = red[2][0] + red[2][1] + red[2][2] + red[2][3] + hb[0];
    out[b * NC_ + 1] = red[3][0] + red[3][1] + red[3][2] + red[3][3] + hb[1];
  }
}

// ---------------- launch ----------------
extern "C" void kernel_launch(void* const* d_in, const int* in_sizes, int n_in,
                              void* d_out, int out_size, void* d_ws, size_t ws_size,
                              hipStream_t stream) {
  if (ws_size < WS_BYTES) return;  // diagnostic guard
  const int*   ids   = (const int*)d_in[0];
  const int*   attn  = (const int*)d_in[1];
  const float* tok   = (const float*)d_in[2];
  const float* cls   = (const float*)d_in[3];
  const float* pos   = (const float*)d_in[4];
  const float* ln1g  = (const float*)d_in[5];
  const float* ln1b  = (const float*)d_in[6];
  const float* qW    = (const float*)d_in[7];
  const float* qb    = (const float*)d_in[8];
  const float* kW    = (const float*)d_in[9];
  const float* kb    = (const float*)d_in[10];
  const float* vW    = (const float*)d_in[11];
  const float* vb    = (const float*)d_in[12];
  const float* oW    = (const float*)d_in[13];
  const float* ob    = (const float*)d_in[14];
  const float* proj  = (const float*)d_in[15];
  const float* ln2g  = (const float*)d_in[16];
  const float* ln2b  = (const float*)d_in[17];
  const float* fc1W  = (const float*)d_in[18];
  const float* fc1b  = (const float*)d_in[19];
  const float* fc2W  = (const float*)d_in[20];
  const float* fc2b  = (const float*)d_in[21];
  const float* lnfg  = (const float*)d_in[22];
  const float* lnfb  = (const float*)d_in[23];
  const float* headW = (const float*)d_in[24];
  const float* headb = (const float*)d_in[25];

  float* ws  = (float*)d_ws;
  u16*   wsu = (u16*)d_ws;
  float* X    = ws + F_X;
  float* KVP  = ws + F_KVP;
  float* KSP  = ws + F_KSP;
  float* KV   = ws + F_KV;
  float* KSUM = ws + F_KS;
  float* QKVB = ws + F_QKVB;
  u16* Ybf  = wsu + S_Y;    // [RP][512]; CTX aliases (temporally disjoint)
  u16* CTXb = wsu + S_Y;
  u16* Vb   = wsu + S_V;    // [RP][512]; HB[RP][2048] starts here (V+KF+QF/2 dead by FFN)
  u16* HB   = wsu + S_V;
  u16* KFb  = wsu + S_KF;   // [RP][1024]
  u16* QFb  = wsu + S_QF;   // [RP][1024]
  u16* Wqkv = wsu + S_WQKV;
  u16* Wo   = wsu + S_WO;
  u16* Wf1  = wsu + S_WF1;
  u16* Wf2  = wsu + S_WF2;
  u16* PT   = wsu + S_PT;

  embed_k<<<BNT, 256, 0, stream>>>(ids, tok, cls, pos, X);
  for (int i = 0; i < L_; ++i) {
    wconv_k<<<3110, 256, 0, stream>>>(qW + (size_t)i * C_ * C_, kW + (size_t)i * C_ * C_,
        vW + (size_t)i * C_ * C_, oW + (size_t)i * C_ * C_,
        fc1W + (size_t)i * C_ * HID_, fc2W + (size_t)i * HID_ * C_,
        proj + (size_t)i * H_ * HD_ * M_,
        qb + i * C_, kb + i * C_, vb + i * C_,
        Wqkv, Wo, Wf1, Wf2, PT, QKVB);
    ln_bf_k<<<RP / 4, 256, 0, stream>>>(X, ln1g + i * C_, ln1b + i * C_, Ybf);
    gemmqkv_k<<<dim3(12, 130), 256, 0, stream>>>(Ybf, Wqkv, QKVB,
        Vb, QFb, KFb, PT, attn);
    kvpart_k<<<dim3(4, 64), 256, 0, stream>>>(KFb, Vb, KVP, KSP);
    kvred_k<<<64, 256, 0, stream>>>(KVP, KSP, KV, KSUM);
    ctx_k<<<dim3(65, 64), 256, 0, stream>>>(QFb, KV, KSUM, CTXb);
    gemm_bf64_k<<<dim3(4, 260), 256, 0, stream>>>(CTXb, 512, Wo, ob + i * C_,
        X, nullptr, 512, 512, MODE_RESID);
    ln_bf_k<<<RP / 4, 256, 0, stream>>>(X, ln2g + i * C_, ln2b + i * C_, Ybf);
    gemm256_k<<<dim3(8, 65), 512, 0, stream>>>(Ybf, 512, Wf1,
        fc1b + i * HID_, nullptr, HB, 2048, 512, MODE_GELU);
    gemm_bf64_k<<<dim3(4, 260), 256, 0, stream>>>(HB, 2048, Wf2,
        fc2b + i * C_, X, nullptr, 512, 2048, MODE_RESID);
  }
  final_k<<<B_, 256, 0, stream>>>(X, lnfg, lnfb, headW, headb, (float*)d_out);
}

// Round 7
// 3362.390 us; speedup vs baseline: 1.0187x; 1.0187x over previous
//
#include <hip/hip_runtime.h>
#include <cmath>
#include <cstdint>
#include <cstddef>

#define B_ 8
#define N_ 2048
#define NT 2049
#define NP 2080                /* padded tokens per batch */
#define C_ 512
#define H_ 8
#define HD_ 64
#define L_ 8
#define M_ 128
#define HID_ 2048
#define NC_ 2
#define BNT (B_*NT)            /* 16392 valid rows */
#define RP (B_*NP)             /* 16640 padded rows = 130*128 */
#define SCALE_ 0.125f
#define LN_EPS_ 1e-5f
#define FEAT_EPS_ 1e-6f

#define MODE_GELU  2
#define MODE_RESID 3

typedef unsigned short u16;
typedef unsigned short u16x8 __attribute__((ext_vector_type(8)));
typedef short frag __attribute__((ext_vector_type(8)));
typedef float f32x4 __attribute__((ext_vector_type(4)));

// ---------------- workspace layout ----------------
// floats
constexpr size_t F_X    = 0;                         // RP*512
constexpr size_t F_KVP  = F_X   + (size_t)RP*512;    // 4*64*8192
constexpr size_t F_KSP  = F_KVP + (size_t)4*64*8192;
constexpr size_t F_KV   = F_KSP + (size_t)4*64*128;
constexpr size_t F_KS   = F_KV  + (size_t)64*M_*HD_;
constexpr size_t F_QKVB = F_KS  + (size_t)64*M_;
constexpr size_t F_END  = F_QKVB + 1536;             // 11,183,616 floats
// u16 region
constexpr size_t S_BASE = 2 * F_END;
constexpr size_t S_Y    = S_BASE;                    // [RP][512]  Y; later KVP2/KSP2, then CTX
constexpr size_t S_V    = S_Y  + (size_t)RP*512;     // [RP][512]  V; HB starts here
constexpr size_t S_KF   = S_V  + (size_t)RP*512;     // [RP][1024] KF
constexpr size_t S_QF   = S_KF + (size_t)RP*1024;    // [RP][1024] QF
constexpr size_t S_WQKV = S_QF + (size_t)RP*1024;    // 1536*512
constexpr size_t S_WO   = S_WQKV + (size_t)1536*512; // 512*512
constexpr size_t S_WF1  = S_WO   + (size_t)512*512;  // 2048*512
constexpr size_t S_WF2  = S_WF1  + (size_t)2048*512; // 512*2048
constexpr size_t S_PT   = S_WF2  + (size_t)512*2048; // 8*128*64
constexpr size_t S_END  = S_PT   + (size_t)8*128*64;
constexpr size_t WS_BYTES = S_END * 2;               // 153,393,152

// ---------------- helpers ----------------
__device__ __forceinline__ float wave_reduce(float v) {
#pragma unroll
  for (int off = 32; off > 0; off >>= 1) v += __shfl_down(v, off, 64);
  return v;
}
__device__ __forceinline__ float b2f(u16 u) {
  union { float f; uint32_t i; } v; v.i = ((uint32_t)u) << 16; return v.f;
}
__device__ __forceinline__ u16 f2b(float f) {
  union { float f; uint32_t i; } v; v.f = f;
  uint32_t r = v.i + 0x7FFF + ((v.i >> 16) & 1);
  return (u16)(r >> 16);
}
__device__ __forceinline__ void gstage(const u16* g, u16* lds_base, int lane) {
#if __has_builtin(__builtin_amdgcn_global_load_lds)
  __builtin_amdgcn_global_load_lds((const __attribute__((address_space(1))) void*)g,
      (__attribute__((address_space(3))) void*)lds_base, 16, 0, 0);
#else
  *(u16x8*)(lds_base + lane * 8) = *(const u16x8*)g;
#endif
}
// XCD-aware bijective block swizzle (T1): contiguous work chunk per XCD.
// Requires nwg % 8 == 0 (all call sites satisfy; guarded anyway).
__device__ __forceinline__ void xcd_swz(int& bx, int& by) {
  int gx = gridDim.x;
  int nwg = gx * gridDim.y;
  int hw = blockIdx.x + blockIdx.y * gx;
  if (nwg & 7) { bx = blockIdx.x; by = blockIdx.y; return; }
  int cpx = nwg >> 3;
  int swz = (hw & 7) * cpx + (hw >> 3);
  bx = swz % gx; by = swz / gx;
}

// ---------------- embedding (grid RP: also zero-fills padding rows) -------
// NaN-hygiene fix #1: X padding rows (n in [NT,NP)) are now hard-zeroed so
// every downstream per-row op on padding rows stays finite.
__global__ __launch_bounds__(256) void embed_k(const int* __restrict__ ids,
    const float* __restrict__ tok, const float* __restrict__ cls,
    const float* __restrict__ pos, float* __restrict__ X) {
  int row = blockIdx.x;
  int b = row / NP, n = row - b * NP;
  int t = threadIdx.x;
  size_t rp = (size_t)row;
  if (n >= NT) {
    X[rp * C_ + t]       = 0.f;
    X[rp * C_ + t + 256] = 0.f;
    return;
  }
  const float* src = (n == 0) ? cls : tok + (size_t)ids[b * N_ + n - 1] * C_;
  X[rp * C_ + t]       = src[t]       + pos[(size_t)n * C_ + t];
  X[rp * C_ + t + 256] = src[t + 256] + pos[(size_t)n * C_ + t + 256];
}

// ---------------- weight transpose + convert + PT + qkv bias (per layer) ----------------
__global__ __launch_bounds__(256) void wconv_k(
    const float* __restrict__ qW, const float* __restrict__ kW,
    const float* __restrict__ vW, const float* __restrict__ oW,
    const float* __restrict__ f1W, const float* __restrict__ f2W,
    const float* __restrict__ projL,
    const float* __restrict__ qb, const float* __restrict__ kb,
    const float* __restrict__ vb,
    u16* __restrict__ Wqkv, u16* __restrict__ Wo,
    u16* __restrict__ Wf1, u16* __restrict__ Wf2,
    u16* __restrict__ PT, float* __restrict__ QKVB) {
  __shared__ float tile[32][33];
  int bid = blockIdx.x, t = threadIdx.x;
  if (bid >= 3104) {            // qkv bias concat
    int i = (bid - 3104) * 256 + t;
    QKVB[i] = (i < 512) ? qb[i] : (i < 1024) ? kb[i - 512] : vb[i - 1024];
    return;
  }
  if (bid >= 3072) {            // PT[h][m][d] = proj[h][d][m]
    int base = (bid - 3072) * 2048 + t * 8;
#pragma unroll
    for (int j = 0; j < 8; ++j) {
      int idx = base + j;
      int h = idx >> 13, rem = idx & 8191, m = rem >> 6, d = rem & 63;
      PT[idx] = f2b(projL[(size_t)h * 8192 + d * 128 + m]);
    }
    return;
  }
  int ti = t >> 5, tj = t & 31;
  const float* src; u16* dst; int k0, n0, ldn, ldk, scol;
  if (bid < 768) {
    int tk = bid & 15, tn = bid >> 4;
    k0 = tk * 32; n0 = tn * 32;
    int sel = n0 >> 9; scol = n0 & 511;
    src = (sel == 0) ? qW : (sel == 1) ? kW : vW;
    ldn = 512; dst = Wqkv; ldk = 512;
  } else if (bid < 1024) {
    int b2 = bid - 768;
    int tk = b2 & 15, tn = b2 >> 4;
    k0 = tk * 32; n0 = tn * 32; scol = n0;
    src = oW; ldn = 512; dst = Wo; ldk = 512;
  } else if (bid < 2048) {
    int b2 = bid - 1024;
    int tk = b2 & 15, tn = b2 >> 4;
    k0 = tk * 32; n0 = tn * 32; scol = n0;
    src = f1W; ldn = 2048; dst = Wf1; ldk = 512;
  } else {
    int b2 = bid - 2048;
    int tk = b2 & 63, tn = b2 >> 6;
    k0 = tk * 32; n0 = tn * 32; scol = n0;
    src = f2W; ldn = 512; dst = Wf2; ldk = 2048;
  }
  const float* sp = src + (size_t)k0 * ldn + scol;
  u16* dp = dst + (size_t)n0 * ldk + k0;
#pragma unroll
  for (int p = 0; p < 4; ++p)
    tile[ti + p * 8][tj] = sp[(size_t)(ti + p * 8) * ldn + tj];
  __syncthreads();
#pragma unroll
  for (int p = 0; p < 4; ++p)
    dp[(size_t)(ti + p * 8) * ldk + tj] = f2b(tile[tj][ti + p * 8]);
}

// ---------------- LayerNorm -> bf16 ----------------
__global__ __launch_bounds__(256) void ln_bf_k(const float* __restrict__ X,
    const float* __restrict__ g, const float* __restrict__ b,
    u16* __restrict__ Y) {
  int w = threadIdx.x >> 6, lane = threadIdx.x & 63;
  int row = blockIdx.x * 4 + w;
  const float* xr = X + (size_t)row * C_;
  float v[8];
  *(float4*)&v[0] = *(const float4*)(xr + lane * 8);
  *(float4*)&v[4] = *(const float4*)(xr + lane * 8 + 4);
  float s = 0.f;
#pragma unroll
  for (int j = 0; j < 8; ++j) s += v[j];
  s = wave_reduce(s);
  float mu = __shfl(s, 0, 64) * (1.0f / C_);
  float sq = 0.f;
#pragma unroll
  for (int j = 0; j < 8; ++j) { float d = v[j] - mu; sq = fmaf(d, d, sq); }
  sq = wave_reduce(sq);
  float rs = rsqrtf(__shfl(sq, 0, 64) * (1.0f / C_) + LN_EPS_);
  float gv[8], bv[8];
  *(float4*)&gv[0] = *(const float4*)(g + lane * 8);
  *(float4*)&gv[4] = *(const float4*)(g + lane * 8 + 4);
  *(float4*)&bv[0] = *(const float4*)(b + lane * 8);
  *(float4*)&bv[4] = *(const float4*)(b + lane * 8 + 4);
  u16x8 o;
#pragma unroll
  for (int j = 0; j < 8; ++j) o[j] = f2b((v[j] - mu) * rs * gv[j] + bv[j]);
  *(u16x8*)(Y + (size_t)row * C_ + lane * 8) = o;
}

// ---------------- bf16 MFMA GEMM (fc1): BM=128, BK=64, 2-phase dbuf pipeline
// T3/T4-lite: double-buffered LDS, counted s_waitcnt vmcnt(8) (never 0 in
// steady state), raw s_barrier (no compiler vmcnt(0) drain). Next tile's 8
// DMA loads stay in flight across the barrier while MFMA runs.
// NOTE: round-4 measured the 256x256 8-phase port of this K=512 GEMM at
// 114.8us vs this kernel's 75.8us — short-K (8 K-tiles) + 520-block tail
// quantization defeat the deep pipeline. Keep this structure.
__global__ __launch_bounds__(256) void gemm_bf_k(
    const u16* __restrict__ A, int lda,
    const u16* __restrict__ Wt,
    const float* __restrict__ bias,
    float* __restrict__ outF, u16* __restrict__ outB,
    int ldc, int Kdim, int mode) {
  __shared__ __align__(16) u16 As[2][128 * 64];
  __shared__ __align__(16) u16 Bs[2][128 * 64];
  const int t = threadIdx.x, w = t >> 6, l = t & 63;
  int bx, by; xcd_swz(bx, by);
  const int row0 = by * 128, col0 = bx * 128;
  const int wm = w & 1, wn = w >> 1;
  const int lm = l & 15, lkb = l >> 4;
  const int lr = l >> 3, lc = l & 7;
  const int kch = (lc ^ lr) * 8;
  const u16* Ag = A  + (size_t)(row0 + lr) * lda  + kch;
  const u16* Bg = Wt + (size_t)(col0 + lr) * Kdim + kch;
  const int sx = lm & 7;
  f32x4 acc[4][4] = {};
  const int nk = Kdim >> 6;
  // prologue: stage tile 0 -> buffer 0
#pragma unroll
  for (int j = 0; j < 4; ++j) {
    int c8 = w * 4 + j;
    gstage(Ag + (size_t)c8 * 8 * lda , &As[0][c8 * 512], l);
    gstage(Bg + (size_t)c8 * 8 * Kdim, &Bs[0][c8 * 512], l);
  }
  for (int kt = 0; kt < nk; ++kt) {
    const int cur = kt & 1;
    if (kt + 1 < nk) {
      const int k0 = (kt + 1) << 6;
#pragma unroll
      for (int j = 0; j < 4; ++j) {
        int c8 = w * 4 + j;
        gstage(Ag + (size_t)c8 * 8 * lda  + k0, &As[cur ^ 1][c8 * 512], l);
        gstage(Bg + (size_t)c8 * 8 * Kdim + k0, &Bs[cur ^ 1][c8 * 512], l);
      }
      asm volatile("s_waitcnt vmcnt(8)" ::: "memory");  // tile kt landed; kt+1 in flight
    } else {
      asm volatile("s_waitcnt vmcnt(0)" ::: "memory");
    }
    __builtin_amdgcn_s_barrier();
    __builtin_amdgcn_sched_barrier(0);
#pragma unroll
    for (int ks = 0; ks < 2; ++ks) {
      frag af[4], bf4[4];
#pragma unroll
      for (int i = 0; i < 4; ++i)
        af[i] = *(const frag*)&As[cur][(wm * 64 + i * 16 + lm) * 64 + (((ks * 4 + lkb) ^ sx) * 8)];
#pragma unroll
      for (int j = 0; j < 4; ++j)
        bf4[j] = *(const frag*)&Bs[cur][(wn * 64 + j * 16 + lm) * 64 + (((ks * 4 + lkb) ^ sx) * 8)];
#pragma unroll
      for (int i = 0; i < 4; ++i)
#pragma unroll
        for (int j = 0; j < 4; ++j)
          acc[i][j] = __builtin_amdgcn_mfma_f32_16x16x32_bf16(af[i], bf4[j], acc[i][j], 0, 0, 0);
    }
    __builtin_amdgcn_sched_barrier(0);
    __builtin_amdgcn_s_barrier();   // all waves done reading buf[cur] before restage
  }
#pragma unroll
  for (int i = 0; i < 4; ++i) {
#pragma unroll
    for (int r = 0; r < 4; ++r) {
      int grow = row0 + wm * 64 + i * 16 + lkb * 4 + r;
      if (mode == MODE_RESID) {
        float* orow = outF + (size_t)grow * ldc + col0;
#pragma unroll
        for (int j = 0; j < 4; ++j) {
          int gc = wn * 64 + j * 16 + lm;
          orow[gc] += acc[i][j][r] + bias[col0 + gc];
        }
      } else { // MODE_GELU (fast sigmoid form)
        u16* orow = outB + (size_t)grow * ldc + col0;
#pragma unroll
        for (int j = 0; j < 4; ++j) {
          int gc = wn * 64 + j * 16 + lm;
          float v = acc[i][j][r] + bias[col0 + gc];
          float u = v * (1.5957691216f + 0.0713548162f * v * v);
          v = v / (1.f + __expf(-u));
          orow[gc] = f2b(v);
        }
      }
    }
  }
}

// ---------------- bf16 MFMA GEMM, BM=64 variant (o-proj / fc2), 2-phase dbuf
__global__ __launch_bounds__(256) void gemm_bf64_k(
    const u16* __restrict__ A, int lda,
    const u16* __restrict__ Wt,
    const float* __restrict__ bias,
    float* __restrict__ outF, u16* __restrict__ outB,
    int ldc, int Kdim, int mode) {
  __shared__ __align__(16) u16 As[2][64 * 64];
  __shared__ __align__(16) u16 Bs[2][128 * 64];
  const int t = threadIdx.x, w = t >> 6, l = t & 63;
  int bx, by; xcd_swz(bx, by);
  const int row0 = by * 64, col0 = bx * 128;
  const int wm = w & 1, wn = w >> 1;          // wave: 32 rows x 64 cols
  const int lm = l & 15, lkb = l >> 4;
  const int lr = l >> 3, lc = l & 7;
  const int kch = (lc ^ lr) * 8;
  const u16* Ag = A  + (size_t)(row0 + lr) * lda  + kch;
  const u16* Bg = Wt + (size_t)(col0 + lr) * Kdim + kch;
  const int sx = lm & 7;
  f32x4 acc[2][4] = {};
  const int nk = Kdim >> 6;
  // prologue: stage tile 0 -> buffer 0 (6 loads/wave: 2 A + 4 B)
#pragma unroll
  for (int q = 0; q < 2; ++q) {
    int c8 = w * 2 + q;
    gstage(Ag + (size_t)c8 * 8 * lda, &As[0][c8 * 512], l);
  }
#pragma unroll
  for (int q = 0; q < 4; ++q) {
    int c8 = w * 4 + q;
    gstage(Bg + (size_t)c8 * 8 * Kdim, &Bs[0][c8 * 512], l);
  }
  for (int kt = 0; kt < nk; ++kt) {
    const int cur = kt & 1;
    if (kt + 1 < nk) {
      const int k0 = (kt + 1) << 6;
#pragma unroll
      for (int q = 0; q < 2; ++q) {
        int c8 = w * 2 + q;
        gstage(Ag + (size_t)c8 * 8 * lda + k0, &As[cur ^ 1][c8 * 512], l);
      }
#pragma unroll
      for (int q = 0; q < 4; ++q) {
        int c8 = w * 4 + q;
        gstage(Bg + (size_t)c8 * 8 * Kdim + k0, &Bs[cur ^ 1][c8 * 512], l);
      }
      asm volatile("s_waitcnt vmcnt(6)" ::: "memory");
    } else {
      asm volatile("s_waitcnt vmcnt(0)" ::: "memory");
    }
    __builtin_amdgcn_s_barrier();
    __builtin_amdgcn_sched_barrier(0);
#pragma unroll
    for (int ks = 0; ks < 2; ++ks) {
      frag af[2], bf4[4];
#pragma unroll
      for (int i = 0; i < 2; ++i)
        af[i] = *(const frag*)&As[cur][(wm * 32 + i * 16 + lm) * 64 + (((ks * 4 + lkb) ^ sx) * 8)];
#pragma unroll
      for (int j = 0; j < 4; ++j)
        bf4[j] = *(const frag*)&Bs[cur][(wn * 64 + j * 16 + lm) * 64 + (((ks * 4 + lkb) ^ sx) * 8)];
#pragma unroll
      for (int i = 0; i < 2; ++i)
#pragma unroll
        for (int j = 0; j < 4; ++j)
          acc[i][j] = __builtin_amdgcn_mfma_f32_16x16x32_bf16(af[i], bf4[j], acc[i][j], 0, 0, 0);
    }
    __builtin_amdgcn_sched_barrier(0);
    __builtin_amdgcn_s_barrier();
  }
#pragma unroll
  for (int i = 0; i < 2; ++i) {
#pragma unroll
    for (int r = 0; r < 4; ++r) {
      int grow = row0 + wm * 32 + i * 16 + lkb * 4 + r;
      if (mode == MODE_RESID) {
        float* orow = outF + (size_t)grow * ldc + col0;
#pragma unroll
        for (int j = 0; j < 4; ++j) {
          int gc = wn * 64 + j * 16 + lm;
          orow[gc] += acc[i][j][r] + bias[col0 + gc];
        }
      } else { // MODE_GELU (fast sigmoid form)
        u16* orow = outB + (size_t)grow * ldc + col0;
#pragma unroll
        for (int j = 0; j < 4; ++j) {
          int gc = wn * 64 + j * 16 + lm;
          float v = acc[i][j][r] + bias[col0 + gc];
          float u = v * (1.5957691216f + 0.0713548162f * v * v);
          v = v / (1.f + __expf(-u));
          orow[gc] = f2b(v);
        }
      }
    }
  }
}

// ---------------- fused QKV GEMM + feature map ----------------
// grid (12, 130) swizzled. col-blocks 0..3: q-heads, 4..7: k-heads, 8..11: v.
// NaN-hygiene fix #2: mask applied as SELECT (mrow==0 -> exact 0), not
// multiply — 0*NaN = NaN would leak garbage rows through the mask.
__global__ __launch_bounds__(256) void gemmqkv_k(
    const u16* __restrict__ A,
    const u16* __restrict__ Wt,          // Wqkv [1536][512]
    const float* __restrict__ bias,      // [1536]
    u16* __restrict__ Vout,              // [RP][512]
    u16* __restrict__ QF, u16* __restrict__ KF,   // [RP][1024]
    const u16* __restrict__ PT,          // [8][128][64]
    const int* __restrict__ attn) {
  __shared__ __align__(16) u16 As[128 * 64];   // later: qtile head0
  __shared__ __align__(16) u16 Bs[128 * 64];   // later: qtile head1
  __shared__ __align__(16) u16 ptb[128 * 64];  // PT[h] staged, swizzled
  __shared__ float sxe[128][2];
  const int t = threadIdx.x, w = t >> 6, l = t & 63;
  int bx, by; xcd_swz(bx, by);
  const int cx = bx;
  const int row0 = by * 128, col0 = cx * 128;
  const int wm = w & 1, wn = w >> 1;
  const int lm = l & 15, lkb = l >> 4;
  const int lr = l >> 3, lc = l & 7;
  const int kch = (lc ^ lr) * 8;
  const u16* Ag = A  + (size_t)(row0 + lr) * 512 + kch;
  const u16* Bg = Wt + (size_t)(col0 + lr) * 512 + kch;
  const int sx = lm & 7;
  f32x4 acc[4][4] = {};
  for (int k0 = 0; k0 < 512; k0 += 64) {
    __syncthreads();
#pragma unroll
    for (int j = 0; j < 4; ++j) {
      int c8 = w * 4 + j;
      gstage(Ag + (size_t)c8 * 8 * 512 + k0, &As[c8 * 512], l);
      gstage(Bg + (size_t)c8 * 8 * 512 + k0, &Bs[c8 * 512], l);
    }
    __syncthreads();
#pragma unroll
    for (int ks = 0; ks < 2; ++ks) {
      frag af[4], bf4[4];
#pragma unroll
      for (int i = 0; i < 4; ++i)
        af[i] = *(const frag*)&As[(wm * 64 + i * 16 + lm) * 64 + (((ks * 4 + lkb) ^ sx) * 8)];
#pragma unroll
      for (int j = 0; j < 4; ++j)
        bf4[j] = *(const frag*)&Bs[(wn * 64 + j * 16 + lm) * 64 + (((ks * 4 + lkb) ^ sx) * 8)];
#pragma unroll
      for (int i = 0; i < 4; ++i)
#pragma unroll
        for (int j = 0; j < 4; ++j)
          acc[i][j] = __builtin_amdgcn_mfma_f32_16x16x32_bf16(af[i], bf4[j], acc[i][j], 0, 0, 0);
    }
  }
  // ---- V path ----
  if (cx >= 8) {
    int c0v = col0 - 1024;
#pragma unroll
    for (int i = 0; i < 4; ++i) {
#pragma unroll
      for (int r = 0; r < 4; ++r) {
        int grow = row0 + wm * 64 + i * 16 + lkb * 4 + r;
        int bb = grow / NP, nn = grow - bb * NP;
        float mrow = (nn == 0) ? 1.f : ((nn < NT) ? (float)attn[bb * N_ + nn - 1] : 0.f);
        u16* orow = Vout + (size_t)grow * 512 + c0v;
#pragma unroll
        for (int j = 0; j < 4; ++j) {
          int gc = wn * 64 + j * 16 + lm;
          float vv = acc[i][j][r] + bias[col0 + gc];
          orow[gc] = f2b(mrow == 0.f ? 0.f : vv * mrow);   // select, not multiply
        }
      }
    }
    return;
  }
  // ---- Q/K path: write scaled/masked tile to LDS (swizzled, per-head) ----
  const bool isq = (cx < 4);
  const int hbase = (isq ? cx : cx - 4) * 2;
  __syncthreads();            // all waves done reading As/Bs
  {
    u16* qt = wn ? Bs : As;
#pragma unroll
    for (int i = 0; i < 4; ++i) {
#pragma unroll
      for (int r = 0; r < 4; ++r) {
        int rl = wm * 64 + i * 16 + lkb * 4 + r;
        float mrow;
        if (isq) mrow = SCALE_;
        else {
          int grow = row0 + rl;
          int bb = grow / NP, nn = grow - bb * NP;
          mrow = (nn == 0) ? 1.f : ((nn < NT) ? (float)attn[bb * N_ + nn - 1] : 0.f);
        }
#pragma unroll
        for (int j = 0; j < 4; ++j) {
          int gcc = j * 16 + lm;
          float v = acc[i][j][r] + bias[col0 + wn * 64 + gcc];
          v = (mrow == 0.f) ? 0.f : v * mrow;              // select, not multiply
          qt[rl * 64 + (((gcc >> 3) ^ (rl & 7)) * 8) + (gcc & 7)] = f2b(v);
        }
      }
    }
  }
  // stage PT for head hbase+0 (independent of qtile)
  {
    const u16* Pg = PT + (size_t)hbase * 8192 + (size_t)lr * 64 + kch;
#pragma unroll
    for (int q = 0; q < 4; ++q) {
      int c8 = w * 4 + q;
      gstage(Pg + (size_t)c8 * 8 * 64, &ptb[c8 * 512], l);
    }
  }
  __syncthreads();
  // ---- 0.5*||x||^2 per (row, head) ----
  {
    int rowi = t >> 1, hf = t & 1;
    const u16* qq = hf ? Bs : As;
    float s = 0.f;
#pragma unroll
    for (int c = 0; c < 8; ++c) {
      const u16* p = &qq[rowi * 64 + ((c ^ (rowi & 7)) * 8)];
#pragma unroll
      for (int e = 0; e < 8; ++e) { float a = b2f(p[e]); s = fmaf(a, a, s); }
    }
    sxe[rowi][hf] = 0.5f * s;
  }
  __syncthreads();
  // ---- feature MFMA per head ----
  u16* OF = isq ? QF : KF;
#pragma unroll
  for (int hp = 0; hp < 2; ++hp) {
    if (hp == 1) {
      __syncthreads();
      const u16* Pg = PT + (size_t)(hbase + 1) * 8192 + (size_t)lr * 64 + kch;
#pragma unroll
      for (int q = 0; q < 4; ++q) {
        int c8 = w * 4 + q;
        gstage(Pg + (size_t)c8 * 8 * 64, &ptb[c8 * 512], l);
      }
      __syncthreads();
    }
    const u16* qt = hp ? Bs : As;
    f32x4 a2[2][8] = {};
#pragma unroll
    for (int ks = 0; ks < 2; ++ks) {
      frag af2[2], bf2[8];
#pragma unroll
      for (int i = 0; i < 2; ++i)
        af2[i] = *(const frag*)&qt[(w * 32 + i * 16 + lm) * 64 + (((ks * 4 + lkb) ^ sx) * 8)];
#pragma unroll
      for (int j = 0; j < 8; ++j)
        bf2[j] = *(const frag*)&ptb[(j * 16 + lm) * 64 + (((ks * 4 + lkb) ^ sx) * 8)];
#pragma unroll
      for (int i = 0; i < 2; ++i)
#pragma unroll
        for (int j = 0; j < 8; ++j)
          a2[i][j] = __builtin_amdgcn_mfma_f32_16x16x32_bf16(af2[i], bf2[j], a2[i][j], 0, 0, 0);
    }
    int hg = hbase + hp;
#pragma unroll
    for (int i = 0; i < 2; ++i) {
#pragma unroll
      for (int r = 0; r < 4; ++r) {
        int R = w * 32 + i * 16 + lkb * 4 + r;
        int grow = row0 + R;
        int bb = grow / NP, nn = grow - bb * NP;
        bool valid = nn < NT;
        float xs = sxe[R][hp];
        u16* orow = OF + (size_t)grow * 1024 + (size_t)hg * 128;
#pragma unroll
        for (int j = 0; j < 8; ++j) {
          int m = j * 16 + lm;
          float v = valid ? (__expf(a2[i][j][r] - xs) + FEAT_EPS_) : 0.f;
          orow[m] = f2b(v);
        }
      }
    }
  }
}

// ---------------- kv partial (pure accumulation, fp32) ----------------
// 8-way ci split (chunks of 264/256 tokens): halves the serial per-block
// token chain vs the old 4x520 split. This kernel is serial-FMA-bound at
// low residency, so more blocks with shorter chains win. Extra partial
// slots (ci 4..7) alias into the temporally-dead Y/CTX region (Y dead after
// gemmqkv; kvred consumes them before ctx overwrites the region).
__global__ __launch_bounds__(256) void kvpart_k(const u16* __restrict__ KF,
    const u16* __restrict__ Vb, float* __restrict__ KVP,
    float* __restrict__ KVP2, float* __restrict__ KSP,
    float* __restrict__ KSP2) {
  int ci = blockIdx.x, bh = blockIdx.y;
  int b = bh >> 3, h = bh & 7;
  const int start = (ci < 4) ? ci * 264 : 1056 + (ci - 4) * 256;
  const int ntile = (ci < 4) ? 33 : 32;
  size_t rb0 = (size_t)b * NP + start;
  __shared__ __align__(16) float kfs[8 * 132];
  __shared__ __align__(16) float vsm[8 * 68];
  int t = threadIdx.x;
  const int d0 = (t & 7) * 8, m0 = (t >> 3) * 4;
  // staging roles: t<128 loads KF (8 tok x 16 groups of 8 m);
  // t in [128,192) loads V (8 tok x 8 groups of 8 d).
  const bool hk = t < 128;
  const bool hv = (t >= 128) && (t < 192);
  const int ktok = t >> 4, kmj = (t & 15) * 8;
  const int vtok = (t - 128) >> 3, vdj = (t & 7) * 8;
  float acc[4][8] = {};
  float ks[4] = {};
  u16x8 rk, rv;
  if (hk) rk = *(const u16x8*)&KF[(rb0 + ktok) * 1024 + h * 128 + kmj];
  if (hv) rv = *(const u16x8*)&Vb[(rb0 + vtok) * 512 + h * 64 + vdj];
  for (int tile = 0; tile < ntile; ++tile) {
    if (hk) {
#pragma unroll
      for (int e = 0; e < 8; ++e) kfs[ktok * 132 + kmj + e] = b2f(rk[e]);
    }
    if (hv) {
#pragma unroll
      for (int e = 0; e < 8; ++e) vsm[vtok * 68 + vdj + e] = b2f(rv[e]);
    }
    __syncthreads();
    if (tile + 1 < ntile) {    // prefetch next tile into registers
      size_t rb = rb0 + (size_t)(tile + 1) * 8;
      if (hk) rk = *(const u16x8*)&KF[(rb + ktok) * 1024 + h * 128 + kmj];
      if (hv) rv = *(const u16x8*)&Vb[(rb + vtok) * 512 + h * 64 + vdj];
    }
#pragma unroll
    for (int tok = 0; tok < 8; ++tok) {
      float kq[4], va[8];
      *(float4*)&kq[0] = *(const float4*)&kfs[tok * 132 + m0];
      *(float4*)&va[0] = *(const float4*)&vsm[tok * 68 + d0];
      *(float4*)&va[4] = *(const float4*)&vsm[tok * 68 + d0 + 4];
#pragma unroll
      for (int mi = 0; mi < 4; ++mi)
#pragma unroll
        for (int di = 0; di < 8; ++di)
          acc[mi][di] = fmaf(kq[mi], va[di], acc[mi][di]);
      if ((t & 7) == 0) { ks[0] += kq[0]; ks[1] += kq[1]; ks[2] += kq[2]; ks[3] += kq[3]; }
    }
    __syncthreads();
  }
  float* dk  = (ci < 4) ? KVP : KVP2;
  float* dsp = (ci < 4) ? KSP : KSP2;
  const int cs = ci & 3;
  size_t base = ((size_t)cs * 64 + bh) * 8192;
#pragma unroll
  for (int mi = 0; mi < 4; ++mi)
#pragma unroll
    for (int di = 0; di < 8; ++di)
      dk[base + (size_t)(m0 + mi) * 64 + d0 + di] = acc[mi][di];
  if ((t & 7) == 0) {
#pragma unroll
    for (int mi = 0; mi < 4; ++mi)
      dsp[((size_t)cs * 64 + bh) * 128 + m0 + mi] = ks[mi];
  }
}

__global__ __launch_bounds__(256) void kvred_k(const float* __restrict__ KVP,
    const float* __restrict__ KVP2, const float* __restrict__ KSP,
    const float* __restrict__ KSP2, float* __restrict__ KV,
    float* __restrict__ KSUM) {
  int bh = blockIdx.x, t = threadIdx.x;
#pragma unroll
  for (int p = 0; p < 32; ++p) {
    int e = p * 256 + t;
    float s = 0.f;
#pragma unroll
    for (int ci = 0; ci < 4; ++ci) {
      s += KVP [((size_t)ci * 64 + bh) * 8192 + e];
      s += KVP2[((size_t)ci * 64 + bh) * 8192 + e];
    }
    KV[(size_t)bh * 8192 + e] = s;
  }
  if (t < 128) {
    float s = 0.f;
#pragma unroll
    for (int ci = 0; ci < 4; ++ci) {
      s += KSP [((size_t)ci * 64 + bh) * 128 + t];
      s += KSP2[((size_t)ci * 64 + bh) * 128 + t];
    }
    KSUM[(size_t)bh * 128 + t] = s;
  }
}

// ---------------- ctx: (qf @ kv) / max(qf . ksum, 1e-6) ----------------
// qfs stored [tok][m] (stride 132) so the PV loop reads q as float4 over m.
// NaN-hygiene fix #3: padding rows (n>=NT) are written as ZERO instead of
// skipped — the CTX region aliases KVP2 fp32 partials whose bit patterns
// can be bf16-NaN; o-proj would otherwise consume them.
__global__ __launch_bounds__(256) void ctx_k(const u16* __restrict__ QF,
    const float* __restrict__ KVg, const float* __restrict__ KSUM,
    u16* __restrict__ CTXo) {
  __shared__ float qfs[32 * 132];
  __shared__ float kvs[128 * 68];
  __shared__ float ksums[128];
  __shared__ float dls[32];
  __shared__ float dpart[8 * 32];
  int t = threadIdx.x;
  int bx, by; xcd_swz(bx, by);
  int bh = by; int b = bh >> 3, h = bh & 7;
  int n0 = bx * 32;
  size_t rbase = (size_t)b * NP + n0;
#pragma unroll
  for (int p = 0; p < 16; ++p) {
    int e = p * 256 + t; int m = e & 127; int tok = e >> 7;
    qfs[tok * 132 + m] = b2f(QF[(rbase + tok) * 1024 + h * 128 + m]);
  }
#pragma unroll
  for (int p = 0; p < 32; ++p) {
    int e = p * 256 + t;
    kvs[(e >> 6) * 68 + (e & 63)] = KVg[(size_t)bh * 8192 + e];
  }
  if (t < 128) ksums[t] = KSUM[bh * 128 + t];
  __syncthreads();
  {
    int j = t & 31, pp = t >> 5;
    float s = 0.f;
#pragma unroll
    for (int mi = 0; mi < 16; ++mi) {
      int m = pp * 16 + mi;
      s = fmaf(qfs[j * 132 + m], ksums[m], s);
    }
    dpart[pp * 32 + j] = s;
  }
  __syncthreads();
  if (t < 32) {
    float den = 0.f;
#pragma unroll
    for (int pp = 0; pp < 8; ++pp) den += dpart[pp * 32 + t];
    dls[t] = 1.f / fmaxf(den, 1e-6f);
  }
  __syncthreads();
  {
    const int d0 = (t & 15) * 4, tok0 = (t >> 4) * 2;
    float acc[2][4] = {};
    const float* q0r = &qfs[tok0 * 132];
    const float* q1r = &qfs[(tok0 + 1) * 132];
#pragma unroll 8
    for (int m4 = 0; m4 < 128; m4 += 4) {
      float4 q0v = *(const float4*)&q0r[m4];
      float4 q1v = *(const float4*)&q1r[m4];
#pragma unroll
      for (int i = 0; i < 4; ++i) {
        float4 kv4 = *(const float4*)&kvs[(m4 + i) * 68 + d0];
        float q0 = (i == 0) ? q0v.x : (i == 1) ? q0v.y : (i == 2) ? q0v.z : q0v.w;
        float q1 = (i == 0) ? q1v.x : (i == 1) ? q1v.y : (i == 2) ? q1v.z : q1v.w;
        acc[0][0] = fmaf(q0, kv4.x, acc[0][0]); acc[0][1] = fmaf(q0, kv4.y, acc[0][1]);
        acc[0][2] = fmaf(q0, kv4.z, acc[0][2]); acc[0][3] = fmaf(q0, kv4.w, acc[0][3]);
        acc[1][0] = fmaf(q1, kv4.x, acc[1][0]); acc[1][1] = fmaf(q1, kv4.y, acc[1][1]);
        acc[1][2] = fmaf(q1, kv4.z, acc[1][2]); acc[1][3] = fmaf(q1, kv4.w, acc[1][3]);
      }
    }
#pragma unroll
    for (int r = 0; r < 2; ++r) {
      int n = n0 + tok0 + r;
      bool pad = (n >= NT);
      float rd = pad ? 0.f : dls[tok0 + r];
      u16* o = CTXo + (rbase + tok0 + r) * C_ + h * HD_ + d0;
#pragma unroll
      for (int c = 0; c < 4; ++c) o[c] = f2b(pad ? 0.f : acc[r][c] * rd);
    }
  }
}

// ---------------- final: LN(x[b,0]) @ headW + headb ----------------
__global__ __launch_bounds__(256) void final_k(const float* __restrict__ X,
    const float* __restrict__ g, const float* __restrict__ beta,
    const float* __restrict__ hW, const float* __restrict__ hb,
    float* __restrict__ out) {
  int b = blockIdx.x, t = threadIdx.x;
  const float* xr = X + (size_t)b * NP * C_;
  float v0 = xr[t], v1 = xr[t + 256];
  __shared__ float red[4][4];
  float s = wave_reduce(v0 + v1);
  if ((t & 63) == 0) red[0][t >> 6] = s;
  __syncthreads();
  float mu = (red[0][0] + red[0][1] + red[0][2] + red[0][3]) * (1.0f / C_);
  float d0 = v0 - mu, d1 = v1 - mu;
  float s2 = wave_reduce(d0 * d0 + d1 * d1);
  if ((t & 63) == 0) red[1][t >> 6] = s2;
  __syncthreads();
  float var = (red[1][0] + red[1][1] + red[1][2] + red[1][3]) * (1.0f / C_);
  float rs = rsqrtf(var + LN_EPS_);
  float n0 = d0 * rs * g[t] + beta[t];
  float n1 = d1 * rs * g[t + 256] + beta[t + 256];
  float p0 = n0 * hW[t * NC_]     + n1 * hW[(t + 256) * NC_];
  float p1 = n0 * hW[t * NC_ + 1] + n1 * hW[(t + 256) * NC_ + 1];
  float t0 = wave_reduce(p0);
  float t1 = wave_reduce(p1);
  if ((t & 63) == 0) { red[2][t >> 6] = t0; red[3][t >> 6] = t1; }
  __syncthreads();
  if (t == 0) {
    out[b * NC_]     = red[2][0] + red[2][1] + red[2][2] + red[2][3] + hb[0];
    out[b * NC_ + 1] = red[3][0] + red[3][1] + red[3][2] + red[3][3] + hb[1];
  }
}

// ---------------- launch ----------------
extern "C" void kernel_launch(void* const* d_in, const int* in_sizes, int n_in,
                              void* d_out, int out_size, void* d_ws, size_t ws_size,
                              hipStream_t stream) {
  if (ws_size < WS_BYTES) return;  // diagnostic guard
  const int*   ids   = (const int*)d_in[0];
  const int*   attn  = (const int*)d_in[1];
  const float* tok   = (const float*)d_in[2];
  const float* cls   = (const float*)d_in[3];
  const float* pos   = (const float*)d_in[4];
  const float* ln1g  = (const float*)d_in[5];
  const float* ln1b  = (const float*)d_in[6];
  const float* qW    = (const float*)d_in[7];
  const float* qb    = (const float*)d_in[8];
  const float* kW    = (const float*)d_in[9];
  const float* kb    = (const float*)d_in[10];
  const float* vW    = (const float*)d_in[11];
  const float* vb    = (const float*)d_in[12];
  const float* oW    = (const float*)d_in[13];
  const float* ob    = (const float*)d_in[14];
  const float* proj  = (const float*)d_in[15];
  const float* ln2g  = (const float*)d_in[16];
  const float* ln2b  = (const float*)d_in[17];
  const float* fc1W  = (const float*)d_in[18];
  const float* fc1b  = (const float*)d_in[19];
  const float* fc2W  = (const float*)d_in[20];
  const float* fc2b  = (const float*)d_in[21];
  const float* lnfg  = (const float*)d_in[22];
  const float* lnfb  = (const float*)d_in[23];
  const float* headW = (const float*)d_in[24];
  const float* headb = (const float*)d_in[25];

  float* ws  = (float*)d_ws;
  u16*   wsu = (u16*)d_ws;
  float* X    = ws + F_X;
  float* KVP  = ws + F_KVP;
  float* KSP  = ws + F_KSP;
  float* KV   = ws + F_KV;
  float* KSUM = ws + F_KS;
  float* QKVB = ws + F_QKVB;
  u16* Ybf  = wsu + S_Y;    // [RP][512]; KVP2/KSP2 + CTX alias (temporally disjoint)
  u16* CTXb = wsu + S_Y;
  float* KVP2 = (float*)(wsu + S_Y);                 // ci 4..7 partials (Y dead then)
  float* KSP2 = KVP2 + (size_t)4 * 64 * 8192;
  u16* Vb   = wsu + S_V;    // [RP][512]; HB[RP][2048] starts here (V+KF+QF/2 dead by FFN)
  u16* HB   = wsu + S_V;
  u16* KFb  = wsu + S_KF;   // [RP][1024]
  u16* QFb  = wsu + S_QF;   // [RP][1024]
  u16* Wqkv = wsu + S_WQKV;
  u16* Wo   = wsu + S_WO;
  u16* Wf1  = wsu + S_WF1;
  u16* Wf2  = wsu + S_WF2;
  u16* PT   = wsu + S_PT;

  embed_k<<<RP, 256, 0, stream>>>(ids, tok, cls, pos, X);
  for (int i = 0; i < L_; ++i) {
    wconv_k<<<3110, 256, 0, stream>>>(qW + (size_t)i * C_ * C_, kW + (size_t)i * C_ * C_,
        vW + (size_t)i * C_ * C_, oW + (size_t)i * C_ * C_,
        fc1W + (size_t)i * C_ * HID_, fc2W + (size_t)i * HID_ * C_,
        proj + (size_t)i * H_ * HD_ * M_,
        qb + i * C_, kb + i * C_, vb + i * C_,
        Wqkv, Wo, Wf1, Wf2, PT, QKVB);
    ln_bf_k<<<RP / 4, 256, 0, stream>>>(X, ln1g + i * C_, ln1b + i * C_, Ybf);
    gemmqkv_k<<<dim3(12, 130), 256, 0, stream>>>(Ybf, Wqkv, QKVB,
        Vb, QFb, KFb, PT, attn);
    kvpart_k<<<dim3(8, 64), 256, 0, stream>>>(KFb, Vb, KVP, KVP2, KSP, KSP2);
    kvred_k<<<64, 256, 0, stream>>>(KVP, KVP2, KSP, KSP2, KV, KSUM);
    ctx_k<<<dim3(65, 64), 256, 0, stream>>>(QFb, KV, KSUM, CTXb);
    gemm_bf64_k<<<dim3(4, 260), 256, 0, stream>>>(CTXb, 512, Wo, ob + i * C_,
        X, nullptr, 512, 512, MODE_RESID);
    ln_bf_k<<<RP / 4, 256, 0, stream>>>(X, ln2g + i * C_, ln2b + i * C_, Ybf);
    gemm_bf_k<<<dim3(16, 130), 256, 0, stream>>>(Ybf, 512, Wf1,
        fc1b + i * HID_, nullptr, HB, 2048, 512, MODE_GELU);
    gemm_bf64_k<<<dim3(4, 260), 256, 0, stream>>>(HB, 2048, Wf2,
        fc2b + i * C_, X, nullptr, 512, 2048, MODE_RESID);
  }
  final_k<<<B_, 256, 0, stream>>>(X, lnfg, lnfb, headW, headb, (float*)d_out);
}

// Round 8
// 3252.776 us; speedup vs baseline: 1.0530x; 1.0337x over previous
//
#include <hip/hip_runtime.h>
#include <cmath>
#include <cstdint>
#include <cstddef>

#define B_ 8
#define N_ 2048
#define NT 2049
#define NP 2080                /* padded tokens per batch */
#define C_ 512
#define H_ 8
#define HD_ 64
#define L_ 8
#define M_ 128
#define HID_ 2048
#define NC_ 2
#define BNT (B_*NT)            /* 16392 valid rows */
#define RP (B_*NP)             /* 16640 padded rows = 130*128 */
#define SCALE_ 0.125f
#define LN_EPS_ 1e-5f
#define FEAT_EPS_ 1e-6f

#define MODE_GELU  2
#define MODE_RESID 3

typedef unsigned short u16;
typedef unsigned short u16x8 __attribute__((ext_vector_type(8)));
typedef short frag __attribute__((ext_vector_type(8)));
typedef float f32x4 __attribute__((ext_vector_type(4)));

// ---------------- workspace layout ----------------
// floats
constexpr size_t F_X    = 0;                         // RP*512
constexpr size_t F_KVP  = F_X   + (size_t)RP*512;    // 4*64*8192
constexpr size_t F_KSP  = F_KVP + (size_t)4*64*8192;
constexpr size_t F_KV   = F_KSP + (size_t)4*64*128;
constexpr size_t F_KS   = F_KV  + (size_t)64*M_*HD_;
constexpr size_t F_QKVB = F_KS  + (size_t)64*M_;
constexpr size_t F_END  = F_QKVB + 1536;             // 11,183,616 floats
// u16 region
constexpr size_t S_BASE = 2 * F_END;
constexpr size_t S_Y    = S_BASE;                    // [RP][512]  Y; later KVP2/KSP2, then CTX
constexpr size_t S_V    = S_Y  + (size_t)RP*512;     // [RP][512]  V; HB starts here
constexpr size_t S_KF   = S_V  + (size_t)RP*512;     // [RP][1024] KF
constexpr size_t S_QF   = S_KF + (size_t)RP*1024;    // [RP][1024] QF
constexpr size_t S_WQKV = S_QF + (size_t)RP*1024;    // 1536*512
constexpr size_t S_WO   = S_WQKV + (size_t)1536*512; // 512*512
constexpr size_t S_WF1  = S_WO   + (size_t)512*512;  // 2048*512
constexpr size_t S_WF2  = S_WF1  + (size_t)2048*512; // 512*2048
constexpr size_t S_PT   = S_WF2  + (size_t)512*2048; // 8*128*64
constexpr size_t S_END  = S_PT   + (size_t)8*128*64;
constexpr size_t WS_BYTES = S_END * 2;               // 153,393,152

// ---------------- helpers ----------------
__device__ __forceinline__ float wave_reduce(float v) {
#pragma unroll
  for (int off = 32; off > 0; off >>= 1) v += __shfl_down(v, off, 64);
  return v;
}
__device__ __forceinline__ float b2f(u16 u) {
  union { float f; uint32_t i; } v; v.i = ((uint32_t)u) << 16; return v.f;
}
__device__ __forceinline__ u16 f2b(float f) {
  union { float f; uint32_t i; } v; v.f = f;
  uint32_t r = v.i + 0x7FFF + ((v.i >> 16) & 1);
  return (u16)(r >> 16);
}
__device__ __forceinline__ void gstage(const u16* g, u16* lds_base, int lane) {
#if __has_builtin(__builtin_amdgcn_global_load_lds)
  __builtin_amdgcn_global_load_lds((const __attribute__((address_space(1))) void*)g,
      (__attribute__((address_space(3))) void*)lds_base, 16, 0, 0);
#else
  *(u16x8*)(lds_base + lane * 8) = *(const u16x8*)g;
#endif
}
// XCD-aware bijective block swizzle (T1): contiguous work chunk per XCD.
// Requires nwg % 8 == 0 (all call sites satisfy; guarded anyway).
__device__ __forceinline__ void xcd_swz(int& bx, int& by) {
  int gx = gridDim.x;
  int nwg = gx * gridDim.y;
  int hw = blockIdx.x + blockIdx.y * gx;
  if (nwg & 7) { bx = blockIdx.x; by = blockIdx.y; return; }
  int cpx = nwg >> 3;
  int swz = (hw & 7) * cpx + (hw >> 3);
  bx = swz % gx; by = swz / gx;
}

// ---------------- embedding (grid RP: also zero-fills padding rows) -------
// NaN-hygiene fix #1: X padding rows (n in [NT,NP)) are hard-zeroed so every
// downstream per-row op on padding rows stays finite. This (together with
// ctx_k's pad-zero write, fix #3) makes plain multiplicative masking safe:
// acc is always finite, so 0*acc == 0.
__global__ __launch_bounds__(256) void embed_k(const int* __restrict__ ids,
    const float* __restrict__ tok, const float* __restrict__ cls,
    const float* __restrict__ pos, float* __restrict__ X) {
  int row = blockIdx.x;
  int b = row / NP, n = row - b * NP;
  int t = threadIdx.x;
  size_t rp = (size_t)row;
  if (n >= NT) {
    X[rp * C_ + t]       = 0.f;
    X[rp * C_ + t + 256] = 0.f;
    return;
  }
  const float* src = (n == 0) ? cls : tok + (size_t)ids[b * N_ + n - 1] * C_;
  X[rp * C_ + t]       = src[t]       + pos[(size_t)n * C_ + t];
  X[rp * C_ + t + 256] = src[t + 256] + pos[(size_t)n * C_ + t + 256];
}

// ---------------- weight transpose + convert + PT + qkv bias (per layer) ----------------
__global__ __launch_bounds__(256) void wconv_k(
    const float* __restrict__ qW, const float* __restrict__ kW,
    const float* __restrict__ vW, const float* __restrict__ oW,
    const float* __restrict__ f1W, const float* __restrict__ f2W,
    const float* __restrict__ projL,
    const float* __restrict__ qb, const float* __restrict__ kb,
    const float* __restrict__ vb,
    u16* __restrict__ Wqkv, u16* __restrict__ Wo,
    u16* __restrict__ Wf1, u16* __restrict__ Wf2,
    u16* __restrict__ PT, float* __restrict__ QKVB) {
  __shared__ float tile[32][33];
  int bid = blockIdx.x, t = threadIdx.x;
  if (bid >= 3104) {            // qkv bias concat
    int i = (bid - 3104) * 256 + t;
    QKVB[i] = (i < 512) ? qb[i] : (i < 1024) ? kb[i - 512] : vb[i - 1024];
    return;
  }
  if (bid >= 3072) {            // PT[h][m][d] = proj[h][d][m]
    int base = (bid - 3072) * 2048 + t * 8;
#pragma unroll
    for (int j = 0; j < 8; ++j) {
      int idx = base + j;
      int h = idx >> 13, rem = idx & 8191, m = rem >> 6, d = rem & 63;
      PT[idx] = f2b(projL[(size_t)h * 8192 + d * 128 + m]);
    }
    return;
  }
  int ti = t >> 5, tj = t & 31;
  const float* src; u16* dst; int k0, n0, ldn, ldk, scol;
  if (bid < 768) {
    int tk = bid & 15, tn = bid >> 4;
    k0 = tk * 32; n0 = tn * 32;
    int sel = n0 >> 9; scol = n0 & 511;
    src = (sel == 0) ? qW : (sel == 1) ? kW : vW;
    ldn = 512; dst = Wqkv; ldk = 512;
  } else if (bid < 1024) {
    int b2 = bid - 768;
    int tk = b2 & 15, tn = b2 >> 4;
    k0 = tk * 32; n0 = tn * 32; scol = n0;
    src = oW; ldn = 512; dst = Wo; ldk = 512;
  } else if (bid < 2048) {
    int b2 = bid - 1024;
    int tk = b2 & 15, tn = b2 >> 4;
    k0 = tk * 32; n0 = tn * 32; scol = n0;
    src = f1W; ldn = 2048; dst = Wf1; ldk = 512;
  } else {
    int b2 = bid - 2048;
    int tk = b2 & 63, tn = b2 >> 6;
    k0 = tk * 32; n0 = tn * 32; scol = n0;
    src = f2W; ldn = 512; dst = Wf2; ldk = 2048;
  }
  const float* sp = src + (size_t)k0 * ldn + scol;
  u16* dp = dst + (size_t)n0 * ldk + k0;
#pragma unroll
  for (int p = 0; p < 4; ++p)
    tile[ti + p * 8][tj] = sp[(size_t)(ti + p * 8) * ldn + tj];
  __syncthreads();
#pragma unroll
  for (int p = 0; p < 4; ++p)
    dp[(size_t)(ti + p * 8) * ldk + tj] = f2b(tile[tj][ti + p * 8]);
}

// ---------------- LayerNorm -> bf16 ----------------
__global__ __launch_bounds__(256) void ln_bf_k(const float* __restrict__ X,
    const float* __restrict__ g, const float* __restrict__ b,
    u16* __restrict__ Y) {
  int w = threadIdx.x >> 6, lane = threadIdx.x & 63;
  int row = blockIdx.x * 4 + w;
  const float* xr = X + (size_t)row * C_;
  float v[8];
  *(float4*)&v[0] = *(const float4*)(xr + lane * 8);
  *(float4*)&v[4] = *(const float4*)(xr + lane * 8 + 4);
  float s = 0.f;
#pragma unroll
  for (int j = 0; j < 8; ++j) s += v[j];
  s = wave_reduce(s);
  float mu = __shfl(s, 0, 64) * (1.0f / C_);
  float sq = 0.f;
#pragma unroll
  for (int j = 0; j < 8; ++j) { float d = v[j] - mu; sq = fmaf(d, d, sq); }
  sq = wave_reduce(sq);
  float rs = rsqrtf(__shfl(sq, 0, 64) * (1.0f / C_) + LN_EPS_);
  float gv[8], bv[8];
  *(float4*)&gv[0] = *(const float4*)(g + lane * 8);
  *(float4*)&gv[4] = *(const float4*)(g + lane * 8 + 4);
  *(float4*)&bv[0] = *(const float4*)(b + lane * 8);
  *(float4*)&bv[4] = *(const float4*)(b + lane * 8 + 4);
  u16x8 o;
#pragma unroll
  for (int j = 0; j < 8; ++j) o[j] = f2b((v[j] - mu) * rs * gv[j] + bv[j]);
  *(u16x8*)(Y + (size_t)row * C_ + lane * 8) = o;
}

// ---------------- bf16 MFMA GEMM (fc1): BM=128, BK=64, 2-phase dbuf pipeline
// T3/T4-lite: double-buffered LDS, counted s_waitcnt vmcnt(8) (never 0 in
// steady state), raw s_barrier (no compiler vmcnt(0) drain). Next tile's 8
// DMA loads stay in flight across the barrier while MFMA runs.
// NOTE: round-4 measured the 256x256 8-phase port of this K=512 GEMM at
// 114.8us vs this kernel's 75.8us — short-K (8 K-tiles) + 520-block tail
// quantization defeat the deep pipeline. Keep this structure.
__global__ __launch_bounds__(256) void gemm_bf_k(
    const u16* __restrict__ A, int lda,
    const u16* __restrict__ Wt,
    const float* __restrict__ bias,
    float* __restrict__ outF, u16* __restrict__ outB,
    int ldc, int Kdim, int mode) {
  __shared__ __align__(16) u16 As[2][128 * 64];
  __shared__ __align__(16) u16 Bs[2][128 * 64];
  const int t = threadIdx.x, w = t >> 6, l = t & 63;
  int bx, by; xcd_swz(bx, by);
  const int row0 = by * 128, col0 = bx * 128;
  const int wm = w & 1, wn = w >> 1;
  const int lm = l & 15, lkb = l >> 4;
  const int lr = l >> 3, lc = l & 7;
  const int kch = (lc ^ lr) * 8;
  const u16* Ag = A  + (size_t)(row0 + lr) * lda  + kch;
  const u16* Bg = Wt + (size_t)(col0 + lr) * Kdim + kch;
  const int sx = lm & 7;
  f32x4 acc[4][4] = {};
  const int nk = Kdim >> 6;
  // prologue: stage tile 0 -> buffer 0
#pragma unroll
  for (int j = 0; j < 4; ++j) {
    int c8 = w * 4 + j;
    gstage(Ag + (size_t)c8 * 8 * lda , &As[0][c8 * 512], l);
    gstage(Bg + (size_t)c8 * 8 * Kdim, &Bs[0][c8 * 512], l);
  }
  for (int kt = 0; kt < nk; ++kt) {
    const int cur = kt & 1;
    if (kt + 1 < nk) {
      const int k0 = (kt + 1) << 6;
#pragma unroll
      for (int j = 0; j < 4; ++j) {
        int c8 = w * 4 + j;
        gstage(Ag + (size_t)c8 * 8 * lda  + k0, &As[cur ^ 1][c8 * 512], l);
        gstage(Bg + (size_t)c8 * 8 * Kdim + k0, &Bs[cur ^ 1][c8 * 512], l);
      }
      asm volatile("s_waitcnt vmcnt(8)" ::: "memory");  // tile kt landed; kt+1 in flight
    } else {
      asm volatile("s_waitcnt vmcnt(0)" ::: "memory");
    }
    __builtin_amdgcn_s_barrier();
    __builtin_amdgcn_sched_barrier(0);
#pragma unroll
    for (int ks = 0; ks < 2; ++ks) {
      frag af[4], bf4[4];
#pragma unroll
      for (int i = 0; i < 4; ++i)
        af[i] = *(const frag*)&As[cur][(wm * 64 + i * 16 + lm) * 64 + (((ks * 4 + lkb) ^ sx) * 8)];
#pragma unroll
      for (int j = 0; j < 4; ++j)
        bf4[j] = *(const frag*)&Bs[cur][(wn * 64 + j * 16 + lm) * 64 + (((ks * 4 + lkb) ^ sx) * 8)];
#pragma unroll
      for (int i = 0; i < 4; ++i)
#pragma unroll
        for (int j = 0; j < 4; ++j)
          acc[i][j] = __builtin_amdgcn_mfma_f32_16x16x32_bf16(af[i], bf4[j], acc[i][j], 0, 0, 0);
    }
    __builtin_amdgcn_sched_barrier(0);
    __builtin_amdgcn_s_barrier();   // all waves done reading buf[cur] before restage
  }
#pragma unroll
  for (int i = 0; i < 4; ++i) {
#pragma unroll
    for (int r = 0; r < 4; ++r) {
      int grow = row0 + wm * 64 + i * 16 + lkb * 4 + r;
      if (mode == MODE_RESID) {
        float* orow = outF + (size_t)grow * ldc + col0;
#pragma unroll
        for (int j = 0; j < 4; ++j) {
          int gc = wn * 64 + j * 16 + lm;
          orow[gc] += acc[i][j][r] + bias[col0 + gc];
        }
      } else { // MODE_GELU (fast sigmoid form)
        u16* orow = outB + (size_t)grow * ldc + col0;
#pragma unroll
        for (int j = 0; j < 4; ++j) {
          int gc = wn * 64 + j * 16 + lm;
          float v = acc[i][j][r] + bias[col0 + gc];
          float u = v * (1.5957691216f + 0.0713548162f * v * v);
          v = v / (1.f + __expf(-u));
          orow[gc] = f2b(v);
        }
      }
    }
  }
}

// ---------------- bf16 MFMA GEMM, BM=64 variant (o-proj / fc2), 2-phase dbuf
__global__ __launch_bounds__(256) void gemm_bf64_k(
    const u16* __restrict__ A, int lda,
    const u16* __restrict__ Wt,
    const float* __restrict__ bias,
    float* __restrict__ outF, u16* __restrict__ outB,
    int ldc, int Kdim, int mode) {
  __shared__ __align__(16) u16 As[2][64 * 64];
  __shared__ __align__(16) u16 Bs[2][128 * 64];
  const int t = threadIdx.x, w = t >> 6, l = t & 63;
  int bx, by; xcd_swz(bx, by);
  const int row0 = by * 64, col0 = bx * 128;
  const int wm = w & 1, wn = w >> 1;          // wave: 32 rows x 64 cols
  const int lm = l & 15, lkb = l >> 4;
  const int lr = l >> 3, lc = l & 7;
  const int kch = (lc ^ lr) * 8;
  const u16* Ag = A  + (size_t)(row0 + lr) * lda  + kch;
  const u16* Bg = Wt + (size_t)(col0 + lr) * Kdim + kch;
  const int sx = lm & 7;
  f32x4 acc[2][4] = {};
  const int nk = Kdim >> 6;
  // prologue: stage tile 0 -> buffer 0 (6 loads/wave: 2 A + 4 B)
#pragma unroll
  for (int q = 0; q < 2; ++q) {
    int c8 = w * 2 + q;
    gstage(Ag + (size_t)c8 * 8 * lda, &As[0][c8 * 512], l);
  }
#pragma unroll
  for (int q = 0; q < 4; ++q) {
    int c8 = w * 4 + q;
    gstage(Bg + (size_t)c8 * 8 * Kdim, &Bs[0][c8 * 512], l);
  }
  for (int kt = 0; kt < nk; ++kt) {
    const int cur = kt & 1;
    if (kt + 1 < nk) {
      const int k0 = (kt + 1) << 6;
#pragma unroll
      for (int q = 0; q < 2; ++q) {
        int c8 = w * 2 + q;
        gstage(Ag + (size_t)c8 * 8 * lda + k0, &As[cur ^ 1][c8 * 512], l);
      }
#pragma unroll
      for (int q = 0; q < 4; ++q) {
        int c8 = w * 4 + q;
        gstage(Bg + (size_t)c8 * 8 * Kdim + k0, &Bs[cur ^ 1][c8 * 512], l);
      }
      asm volatile("s_waitcnt vmcnt(6)" ::: "memory");
    } else {
      asm volatile("s_waitcnt vmcnt(0)" ::: "memory");
    }
    __builtin_amdgcn_s_barrier();
    __builtin_amdgcn_sched_barrier(0);
#pragma unroll
    for (int ks = 0; ks < 2; ++ks) {
      frag af[2], bf4[4];
#pragma unroll
      for (int i = 0; i < 2; ++i)
        af[i] = *(const frag*)&As[cur][(wm * 32 + i * 16 + lm) * 64 + (((ks * 4 + lkb) ^ sx) * 8)];
#pragma unroll
      for (int j = 0; j < 4; ++j)
        bf4[j] = *(const frag*)&Bs[cur][(wn * 64 + j * 16 + lm) * 64 + (((ks * 4 + lkb) ^ sx) * 8)];
#pragma unroll
      for (int i = 0; i < 2; ++i)
#pragma unroll
        for (int j = 0; j < 4; ++j)
          acc[i][j] = __builtin_amdgcn_mfma_f32_16x16x32_bf16(af[i], bf4[j], acc[i][j], 0, 0, 0);
    }
    __builtin_amdgcn_sched_barrier(0);
    __builtin_amdgcn_s_barrier();
  }
#pragma unroll
  for (int i = 0; i < 2; ++i) {
#pragma unroll
    for (int r = 0; r < 4; ++r) {
      int grow = row0 + wm * 32 + i * 16 + lkb * 4 + r;
      if (mode == MODE_RESID) {
        float* orow = outF + (size_t)grow * ldc + col0;
#pragma unroll
        for (int j = 0; j < 4; ++j) {
          int gc = wn * 64 + j * 16 + lm;
          orow[gc] += acc[i][j][r] + bias[col0 + gc];
        }
      } else { // MODE_GELU (fast sigmoid form)
        u16* orow = outB + (size_t)grow * ldc + col0;
#pragma unroll
        for (int j = 0; j < 4; ++j) {
          int gc = wn * 64 + j * 16 + lm;
          float v = acc[i][j][r] + bias[col0 + gc];
          float u = v * (1.5957691216f + 0.0713548162f * v * v);
          v = v / (1.f + __expf(-u));
          orow[gc] = f2b(v);
        }
      }
    }
  }
}

// ---------------- fused QKV GEMM + feature map ----------------
// grid (12, 130) swizzled. col-blocks 0..3: q-heads, 4..7: k-heads, 8..11: v.
// Masking is plain MULTIPLY (round-3 form): safe because embed_k zero-fills
// X padding (acc always finite) and ctx_k zero-writes CTX padding.
// Round-7 A/B: the compare+select form coincided with gemmqkv 75->110us.
__global__ __launch_bounds__(256) void gemmqkv_k(
    const u16* __restrict__ A,
    const u16* __restrict__ Wt,          // Wqkv [1536][512]
    const float* __restrict__ bias,      // [1536]
    u16* __restrict__ Vout,              // [RP][512]
    u16* __restrict__ QF, u16* __restrict__ KF,   // [RP][1024]
    const u16* __restrict__ PT,          // [8][128][64]
    const int* __restrict__ attn) {
  __shared__ __align__(16) u16 As[128 * 64];   // later: qtile head0
  __shared__ __align__(16) u16 Bs[128 * 64];   // later: qtile head1
  __shared__ __align__(16) u16 ptb[128 * 64];  // PT[h] staged, swizzled
  __shared__ float sxe[128][2];
  const int t = threadIdx.x, w = t >> 6, l = t & 63;
  int bx, by; xcd_swz(bx, by);
  const int cx = bx;
  const int row0 = by * 128, col0 = cx * 128;
  const int wm = w & 1, wn = w >> 1;
  const int lm = l & 15, lkb = l >> 4;
  const int lr = l >> 3, lc = l & 7;
  const int kch = (lc ^ lr) * 8;
  const u16* Ag = A  + (size_t)(row0 + lr) * 512 + kch;
  const u16* Bg = Wt + (size_t)(col0 + lr) * 512 + kch;
  const int sx = lm & 7;
  f32x4 acc[4][4] = {};
  for (int k0 = 0; k0 < 512; k0 += 64) {
    __syncthreads();
#pragma unroll
    for (int j = 0; j < 4; ++j) {
      int c8 = w * 4 + j;
      gstage(Ag + (size_t)c8 * 8 * 512 + k0, &As[c8 * 512], l);
      gstage(Bg + (size_t)c8 * 8 * 512 + k0, &Bs[c8 * 512], l);
    }
    __syncthreads();
#pragma unroll
    for (int ks = 0; ks < 2; ++ks) {
      frag af[4], bf4[4];
#pragma unroll
      for (int i = 0; i < 4; ++i)
        af[i] = *(const frag*)&As[(wm * 64 + i * 16 + lm) * 64 + (((ks * 4 + lkb) ^ sx) * 8)];
#pragma unroll
      for (int j = 0; j < 4; ++j)
        bf4[j] = *(const frag*)&Bs[(wn * 64 + j * 16 + lm) * 64 + (((ks * 4 + lkb) ^ sx) * 8)];
#pragma unroll
      for (int i = 0; i < 4; ++i)
#pragma unroll
        for (int j = 0; j < 4; ++j)
          acc[i][j] = __builtin_amdgcn_mfma_f32_16x16x32_bf16(af[i], bf4[j], acc[i][j], 0, 0, 0);
    }
  }
  // ---- V path ----
  if (cx >= 8) {
    int c0v = col0 - 1024;
#pragma unroll
    for (int i = 0; i < 4; ++i) {
#pragma unroll
      for (int r = 0; r < 4; ++r) {
        int grow = row0 + wm * 64 + i * 16 + lkb * 4 + r;
        int bb = grow / NP, nn = grow - bb * NP;
        float mrow = (nn == 0) ? 1.f : ((nn < NT) ? (float)attn[bb * N_ + nn - 1] : 0.f);
        u16* orow = Vout + (size_t)grow * 512 + c0v;
#pragma unroll
        for (int j = 0; j < 4; ++j) {
          int gc = wn * 64 + j * 16 + lm;
          orow[gc] = f2b((acc[i][j][r] + bias[col0 + gc]) * mrow);
        }
      }
    }
    return;
  }
  // ---- Q/K path: write scaled/masked tile to LDS (swizzled, per-head) ----
  const bool isq = (cx < 4);
  const int hbase = (isq ? cx : cx - 4) * 2;
  __syncthreads();            // all waves done reading As/Bs
  {
    u16* qt = wn ? Bs : As;
#pragma unroll
    for (int i = 0; i < 4; ++i) {
#pragma unroll
      for (int r = 0; r < 4; ++r) {
        int rl = wm * 64 + i * 16 + lkb * 4 + r;
        float mrow;
        if (isq) mrow = SCALE_;
        else {
          int grow = row0 + rl;
          int bb = grow / NP, nn = grow - bb * NP;
          mrow = (nn == 0) ? 1.f : ((nn < NT) ? (float)attn[bb * N_ + nn - 1] : 0.f);
        }
#pragma unroll
        for (int j = 0; j < 4; ++j) {
          int gcc = j * 16 + lm;
          float v = (acc[i][j][r] + bias[col0 + wn * 64 + gcc]) * mrow;
          qt[rl * 64 + (((gcc >> 3) ^ (rl & 7)) * 8) + (gcc & 7)] = f2b(v);
        }
      }
    }
  }
  // stage PT for head hbase+0 (independent of qtile)
  {
    const u16* Pg = PT + (size_t)hbase * 8192 + (size_t)lr * 64 + kch;
#pragma unroll
    for (int q = 0; q < 4; ++q) {
      int c8 = w * 4 + q;
      gstage(Pg + (size_t)c8 * 8 * 64, &ptb[c8 * 512], l);
    }
  }
  __syncthreads();
  // ---- 0.5*||x||^2 per (row, head) ----
  {
    int rowi = t >> 1, hf = t & 1;
    const u16* qq = hf ? Bs : As;
    float s = 0.f;
#pragma unroll
    for (int c = 0; c < 8; ++c) {
      const u16* p = &qq[rowi * 64 + ((c ^ (rowi & 7)) * 8)];
#pragma unroll
      for (int e = 0; e < 8; ++e) { float a = b2f(p[e]); s = fmaf(a, a, s); }
    }
    sxe[rowi][hf] = 0.5f * s;
  }
  __syncthreads();
  // ---- feature MFMA per head ----
  u16* OF = isq ? QF : KF;
#pragma unroll
  for (int hp = 0; hp < 2; ++hp) {
    if (hp == 1) {
      __syncthreads();
      const u16* Pg = PT + (size_t)(hbase + 1) * 8192 + (size_t)lr * 64 + kch;
#pragma unroll
      for (int q = 0; q < 4; ++q) {
        int c8 = w * 4 + q;
        gstage(Pg + (size_t)c8 * 8 * 64, &ptb[c8 * 512], l);
      }
      __syncthreads();
    }
    const u16* qt = hp ? Bs : As;
    f32x4 a2[2][8] = {};
#pragma unroll
    for (int ks = 0; ks < 2; ++ks) {
      frag af2[2], bf2[8];
#pragma unroll
      for (int i = 0; i < 2; ++i)
        af2[i] = *(const frag*)&qt[(w * 32 + i * 16 + lm) * 64 + (((ks * 4 + lkb) ^ sx) * 8)];
#pragma unroll
      for (int j = 0; j < 8; ++j)
        bf2[j] = *(const frag*)&ptb[(j * 16 + lm) * 64 + (((ks * 4 + lkb) ^ sx) * 8)];
#pragma unroll
      for (int i = 0; i < 2; ++i)
#pragma unroll
        for (int j = 0; j < 8; ++j)
          a2[i][j] = __builtin_amdgcn_mfma_f32_16x16x32_bf16(af2[i], bf2[j], a2[i][j], 0, 0, 0);
    }
    int hg = hbase + hp;
#pragma unroll
    for (int i = 0; i < 2; ++i) {
#pragma unroll
      for (int r = 0; r < 4; ++r) {
        int R = w * 32 + i * 16 + lkb * 4 + r;
        int grow = row0 + R;
        int bb = grow / NP, nn = grow - bb * NP;
        bool valid = nn < NT;
        float xs = sxe[R][hp];
        u16* orow = OF + (size_t)grow * 1024 + (size_t)hg * 128;
#pragma unroll
        for (int j = 0; j < 8; ++j) {
          int m = j * 16 + lm;
          float v = valid ? (__expf(a2[i][j][r] - xs) + FEAT_EPS_) : 0.f;
          orow[m] = f2b(v);
        }
      }
    }
  }
}

// ---------------- kv partial (pure accumulation, fp32) ----------------
// 8-way ci split (chunks of 264/256 tokens): halves the serial per-block
// token chain vs the old 4x520 split. This kernel is serial-FMA-bound at
// low residency, so more blocks with shorter chains win. Extra partial
// slots (ci 4..7) alias into the temporally-dead Y/CTX region (Y dead after
// gemmqkv; kvred consumes them before ctx overwrites the region).
__global__ __launch_bounds__(256) void kvpart_k(const u16* __restrict__ KF,
    const u16* __restrict__ Vb, float* __restrict__ KVP,
    float* __restrict__ KVP2, float* __restrict__ KSP,
    float* __restrict__ KSP2) {
  int ci = blockIdx.x, bh = blockIdx.y;
  int b = bh >> 3, h = bh & 7;
  const int start = (ci < 4) ? ci * 264 : 1056 + (ci - 4) * 256;
  const int ntile = (ci < 4) ? 33 : 32;
  size_t rb0 = (size_t)b * NP + start;
  __shared__ __align__(16) float kfs[8 * 132];
  __shared__ __align__(16) float vsm[8 * 68];
  int t = threadIdx.x;
  const int d0 = (t & 7) * 8, m0 = (t >> 3) * 4;
  // staging roles: t<128 loads KF (8 tok x 16 groups of 8 m);
  // t in [128,192) loads V (8 tok x 8 groups of 8 d).
  const bool hk = t < 128;
  const bool hv = (t >= 128) && (t < 192);
  const int ktok = t >> 4, kmj = (t & 15) * 8;
  const int vtok = (t - 128) >> 3, vdj = (t & 7) * 8;
  float acc[4][8] = {};
  float ks[4] = {};
  u16x8 rk, rv;
  if (hk) rk = *(const u16x8*)&KF[(rb0 + ktok) * 1024 + h * 128 + kmj];
  if (hv) rv = *(const u16x8*)&Vb[(rb0 + vtok) * 512 + h * 64 + vdj];
  for (int tile = 0; tile < ntile; ++tile) {
    if (hk) {
#pragma unroll
      for (int e = 0; e < 8; ++e) kfs[ktok * 132 + kmj + e] = b2f(rk[e]);
    }
    if (hv) {
#pragma unroll
      for (int e = 0; e < 8; ++e) vsm[vtok * 68 + vdj + e] = b2f(rv[e]);
    }
    __syncthreads();
    if (tile + 1 < ntile) {    // prefetch next tile into registers
      size_t rb = rb0 + (size_t)(tile + 1) * 8;
      if (hk) rk = *(const u16x8*)&KF[(rb + ktok) * 1024 + h * 128 + kmj];
      if (hv) rv = *(const u16x8*)&Vb[(rb + vtok) * 512 + h * 64 + vdj];
    }
#pragma unroll
    for (int tok = 0; tok < 8; ++tok) {
      float kq[4], va[8];
      *(float4*)&kq[0] = *(const float4*)&kfs[tok * 132 + m0];
      *(float4*)&va[0] = *(const float4*)&vsm[tok * 68 + d0];
      *(float4*)&va[4] = *(const float4*)&vsm[tok * 68 + d0 + 4];
#pragma unroll
      for (int mi = 0; mi < 4; ++mi)
#pragma unroll
        for (int di = 0; di < 8; ++di)
          acc[mi][di] = fmaf(kq[mi], va[di], acc[mi][di]);
      if ((t & 7) == 0) { ks[0] += kq[0]; ks[1] += kq[1]; ks[2] += kq[2]; ks[3] += kq[3]; }
    }
    __syncthreads();
  }
  float* dk  = (ci < 4) ? KVP : KVP2;
  float* dsp = (ci < 4) ? KSP : KSP2;
  const int cs = ci & 3;
  size_t base = ((size_t)cs * 64 + bh) * 8192;
#pragma unroll
  for (int mi = 0; mi < 4; ++mi)
#pragma unroll
    for (int di = 0; di < 8; ++di)
      dk[base + (size_t)(m0 + mi) * 64 + d0 + di] = acc[mi][di];
  if ((t & 7) == 0) {
#pragma unroll
    for (int mi = 0; mi < 4; ++mi)
      dsp[((size_t)cs * 64 + bh) * 128 + m0 + mi] = ks[mi];
  }
}

__global__ __launch_bounds__(256) void kvred_k(const float* __restrict__ KVP,
    const float* __restrict__ KVP2, const float* __restrict__ KSP,
    const float* __restrict__ KSP2, float* __restrict__ KV,
    float* __restrict__ KSUM) {
  int bh = blockIdx.x, t = threadIdx.x;
#pragma unroll
  for (int p = 0; p < 32; ++p) {
    int e = p * 256 + t;
    float s = 0.f;
#pragma unroll
    for (int ci = 0; ci < 4; ++ci) {
      s += KVP [((size_t)ci * 64 + bh) * 8192 + e];
      s += KVP2[((size_t)ci * 64 + bh) * 8192 + e];
    }
    KV[(size_t)bh * 8192 + e] = s;
  }
  if (t < 128) {
    float s = 0.f;
#pragma unroll
    for (int ci = 0; ci < 4; ++ci) {
      s += KSP [((size_t)ci * 64 + bh) * 128 + t];
      s += KSP2[((size_t)ci * 64 + bh) * 128 + t];
    }
    KSUM[(size_t)bh * 128 + t] = s;
  }
}

// ---------------- ctx: (qf @ kv) / max(qf . ksum, 1e-6) ----------------
// qfs stored [tok][m] (stride 132) so the PV loop reads q as float4 over m.
// NaN-hygiene fix #3: padding rows (n>=NT) are written as ZERO instead of
// skipped — the CTX region aliases KVP2 fp32 partials whose bit patterns
// can be bf16-NaN; o-proj would otherwise consume them.
__global__ __launch_bounds__(256) void ctx_k(const u16* __restrict__ QF,
    const float* __restrict__ KVg, const float* __restrict__ KSUM,
    u16* __restrict__ CTXo) {
  __shared__ float qfs[32 * 132];
  __shared__ float kvs[128 * 68];
  __shared__ float ksums[128];
  __shared__ float dls[32];
  __shared__ float dpart[8 * 32];
  int t = threadIdx.x;
  int bx, by; xcd_swz(bx, by);
  int bh = by; int b = bh >> 3, h = bh & 7;
  int n0 = bx * 32;
  size_t rbase = (size_t)b * NP + n0;
#pragma unroll
  for (int p = 0; p < 16; ++p) {
    int e = p * 256 + t; int m = e & 127; int tok = e >> 7;
    qfs[tok * 132 + m] = b2f(QF[(rbase + tok) * 1024 + h * 128 + m]);
  }
#pragma unroll
  for (int p = 0; p < 32; ++p) {
    int e = p * 256 + t;
    kvs[(e >> 6) * 68 + (e & 63)] = KVg[(size_t)bh * 8192 + e];
  }
  if (t < 128) ksums[t] = KSUM[bh * 128 + t];
  __syncthreads();
  {
    int j = t & 31, pp = t >> 5;
    float s = 0.f;
#pragma unroll
    for (int mi = 0; mi < 16; ++mi) {
      int m = pp * 16 + mi;
      s = fmaf(qfs[j * 132 + m], ksums[m], s);
    }
    dpart[pp * 32 + j] = s;
  }
  __syncthreads();
  if (t < 32) {
    float den = 0.f;
#pragma unroll
    for (int pp = 0; pp < 8; ++pp) den += dpart[pp * 32 + t];
    dls[t] = 1.f / fmaxf(den, 1e-6f);
  }
  __syncthreads();
  {
    const int d0 = (t & 15) * 4, tok0 = (t >> 4) * 2;
    float acc[2][4] = {};
    const float* q0r = &qfs[tok0 * 132];
    const float* q1r = &qfs[(tok0 + 1) * 132];
#pragma unroll 8
    for (int m4 = 0; m4 < 128; m4 += 4) {
      float4 q0v = *(const float4*)&q0r[m4];
      float4 q1v = *(const float4*)&q1r[m4];
#pragma unroll
      for (int i = 0; i < 4; ++i) {
        float4 kv4 = *(const float4*)&kvs[(m4 + i) * 68 + d0];
        float q0 = (i == 0) ? q0v.x : (i == 1) ? q0v.y : (i == 2) ? q0v.z : q0v.w;
        float q1 = (i == 0) ? q1v.x : (i == 1) ? q1v.y : (i == 2) ? q1v.z : q1v.w;
        acc[0][0] = fmaf(q0, kv4.x, acc[0][0]); acc[0][1] = fmaf(q0, kv4.y, acc[0][1]);
        acc[0][2] = fmaf(q0, kv4.z, acc[0][2]); acc[0][3] = fmaf(q0, kv4.w, acc[0][3]);
        acc[1][0] = fmaf(q1, kv4.x, acc[1][0]); acc[1][1] = fmaf(q1, kv4.y, acc[1][1]);
        acc[1][2] = fmaf(q1, kv4.z, acc[1][2]); acc[1][3] = fmaf(q1, kv4.w, acc[1][3]);
      }
    }
#pragma unroll
    for (int r = 0; r < 2; ++r) {
      int n = n0 + tok0 + r;
      bool pad = (n >= NT);
      float rd = pad ? 0.f : dls[tok0 + r];
      u16* o = CTXo + (rbase + tok0 + r) * C_ + h * HD_ + d0;
#pragma unroll
      for (int c = 0; c < 4; ++c) o[c] = f2b(pad ? 0.f : acc[r][c] * rd);
    }
  }
}

// ---------------- final: LN(x[b,0]) @ headW + headb ----------------
__global__ __launch_bounds__(256) void final_k(const float* __restrict__ X,
    const float* __restrict__ g, const float* __restrict__ beta,
    const float* __restrict__ hW, const float* __restrict__ hb,
    float* __restrict__ out) {
  int b = blockIdx.x, t = threadIdx.x;
  const float* xr = X + (size_t)b * NP * C_;
  float v0 = xr[t], v1 = xr[t + 256];
  __shared__ float red[4][4];
  float s = wave_reduce(v0 + v1);
  if ((t & 63) == 0) red[0][t >> 6] = s;
  __syncthreads();
  float mu = (red[0][0] + red[0][1] + red[0][2] + red[0][3]) * (1.0f / C_);
  float d0 = v0 - mu, d1 = v1 - mu;
  float s2 = wave_reduce(d0 * d0 + d1 * d1);
  if ((t & 63) == 0) red[1][t >> 6] = s2;
  __syncthreads();
  float var = (red[1][0] + red[1][1] + red[1][2] + red[1][3]) * (1.0f / C_);
  float rs = rsqrtf(var + LN_EPS_);
  float n0 = d0 * rs * g[t] + beta[t];
  float n1 = d1 * rs * g[t + 256] + beta[t + 256];
  float p0 = n0 * hW[t * NC_]     + n1 * hW[(t + 256) * NC_];
  float p1 = n0 * hW[t * NC_ + 1] + n1 * hW[(t + 256) * NC_ + 1];
  float t0 = wave_reduce(p0);
  float t1 = wave_reduce(p1);
  if ((t & 63) == 0) { red[2][t >> 6] = t0; red[3][t >> 6] = t1; }
  __syncthreads();
  if (t == 0) {
    out[b * NC_]     = red[2][0] + red[2][1] + red[2][2] + red[2][3] + hb[0];
    out[b * NC_ + 1] = red[3][0] + red[3][1] + red[3][2] + red[3][3] + hb[1];
  }
}

// ---------------- launch ----------------
extern "C" void kernel_launch(void* const* d_in, const int* in_sizes, int n_in,
                              void* d_out, int out_size, void* d_ws, size_t ws_size,
                              hipStream_t stream) {
  if (ws_size < WS_BYTES) return;  // diagnostic guard
  const int*   ids   = (const int*)d_in[0];
  const int*   attn  = (const int*)d_in[1];
  const float* tok   = (const float*)d_in[2];
  const float* cls   = (const float*)d_in[3];
  const float* pos   = (const float*)d_in[4];
  const float* ln1g  = (const float*)d_in[5];
  const float* ln1b  = (const float*)d_in[6];
  const float* qW    = (const float*)d_in[7];
  const float* qb    = (const float*)d_in[8];
  const float* kW    = (const float*)d_in[9];
  const float* kb    = (const float*)d_in[10];
  const float* vW    = (const float*)d_in[11];
  const float* vb    = (const float*)d_in[12];
  const float* oW    = (const float*)d_in[13];
  const float* ob    = (const float*)d_in[14];
  const float* proj  = (const float*)d_in[15];
  const float* ln2g  = (const float*)d_in[16];
  const float* ln2b  = (const float*)d_in[17];
  const float* fc1W  = (const float*)d_in[18];
  const float* fc1b  = (const float*)d_in[19];
  const float* fc2W  = (const float*)d_in[20];
  const float* fc2b  = (const float*)d_in[21];
  const float* lnfg  = (const float*)d_in[22];
  const float* lnfb  = (const float*)d_in[23];
  const float* headW = (const float*)d_in[24];
  const float* headb = (const float*)d_in[25];

  float* ws  = (float*)d_ws;
  u16*   wsu = (u16*)d_ws;
  float* X    = ws + F_X;
  float* KVP  = ws + F_KVP;
  float* KSP  = ws + F_KSP;
  float* KV   = ws + F_KV;
  float* KSUM = ws + F_KS;
  float* QKVB = ws + F_QKVB;
  u16* Ybf  = wsu + S_Y;    // [RP][512]; KVP2/KSP2 + CTX alias (temporally disjoint)
  u16* CTXb = wsu + S_Y;
  float* KVP2 = (float*)(wsu + S_Y);                 // ci 4..7 partials (Y dead then)
  float* KSP2 = KVP2 + (size_t)4 * 64 * 8192;
  u16* Vb   = wsu + S_V;    // [RP][512]; HB[RP][2048] starts here (V+KF+QF/2 dead by FFN)
  u16* HB   = wsu + S_V;
  u16* KFb  = wsu + S_KF;   // [RP][1024]
  u16* QFb  = wsu + S_QF;   // [RP][1024]
  u16* Wqkv = wsu + S_WQKV;
  u16* Wo   = wsu + S_WO;
  u16* Wf1  = wsu + S_WF1;
  u16* Wf2  = wsu + S_WF2;
  u16* PT   = wsu + S_PT;

  embed_k<<<RP, 256, 0, stream>>>(ids, tok, cls, pos, X);
  for (int i = 0; i < L_; ++i) {
    wconv_k<<<3110, 256, 0, stream>>>(qW + (size_t)i * C_ * C_, kW + (size_t)i * C_ * C_,
        vW + (size_t)i * C_ * C_, oW + (size_t)i * C_ * C_,
        fc1W + (size_t)i * C_ * HID_, fc2W + (size_t)i * HID_ * C_,
        proj + (size_t)i * H_ * HD_ * M_,
        qb + i * C_, kb + i * C_, vb + i * C_,
        Wqkv, Wo, Wf1, Wf2, PT, QKVB);
    ln_bf_k<<<RP / 4, 256, 0, stream>>>(X, ln1g + i * C_, ln1b + i * C_, Ybf);
    gemmqkv_k<<<dim3(12, 130), 256, 0, stream>>>(Ybf, Wqkv, QKVB,
        Vb, QFb, KFb, PT, attn);
    kvpart_k<<<dim3(8, 64), 256, 0, stream>>>(KFb, Vb, KVP, KVP2, KSP, KSP2);
    kvred_k<<<64, 256, 0, stream>>>(KVP, KVP2, KSP, KSP2, KV, KSUM);
    ctx_k<<<dim3(65, 64), 256, 0, stream>>>(QFb, KV, KSUM, CTXb);
    gemm_bf64_k<<<dim3(4, 260), 256, 0, stream>>>(CTXb, 512, Wo, ob + i * C_,
        X, nullptr, 512, 512, MODE_RESID);
    ln_bf_k<<<RP / 4, 256, 0, stream>>>(X, ln2g + i * C_, ln2b + i * C_, Ybf);
    gemm_bf_k<<<dim3(16, 130), 256, 0, stream>>>(Ybf, 512, Wf1,
        fc1b + i * HID_, nullptr, HB, 2048, 512, MODE_GELU);
    gemm_bf64_k<<<dim3(4, 260), 256, 0, stream>>>(HB, 2048, Wf2,
        fc2b + i * C_, X, nullptr, 512, 2048, MODE_RESID);
  }
  final_k<<<B_, 256, 0, stream>>>(X, lnfg, lnfb, headW, headb, (float*)d_out);
}

// Round 9
// 3113.350 us; speedup vs baseline: 1.1001x; 1.0448x over previous
//
#include <hip/hip_runtime.h>
#include <cmath>
#include <cstdint>
#include <cstddef>

#define B_ 8
#define N_ 2048
#define NT 2049
#define NP 2080                /* padded tokens per batch */
#define C_ 512
#define H_ 8
#define HD_ 64
#define L_ 8
#define M_ 128
#define HID_ 2048
#define NC_ 2
#define BNT (B_*NT)            /* 16392 valid rows */
#define RP (B_*NP)             /* 16640 padded rows = 130*128 */
#define SCALE_ 0.125f
#define LN_EPS_ 1e-5f
#define FEAT_EPS_ 1e-6f

#define MODE_GELU  2
#define MODE_RESID 3

typedef unsigned short u16;
typedef unsigned short u16x8 __attribute__((ext_vector_type(8)));
typedef short frag __attribute__((ext_vector_type(8)));
typedef float f32x4 __attribute__((ext_vector_type(4)));

// ---------------- workspace layout ----------------
// floats
constexpr size_t F_X    = 0;                         // RP*512
constexpr size_t F_KVP  = F_X   + (size_t)RP*512;    // 4*64*8192
constexpr size_t F_KSP  = F_KVP + (size_t)4*64*8192;
constexpr size_t F_KV   = F_KSP + (size_t)4*64*128;
constexpr size_t F_KS   = F_KV  + (size_t)64*M_*HD_;
constexpr size_t F_QKVB = F_KS  + (size_t)64*M_;
constexpr size_t F_END  = F_QKVB + 1536;             // 11,183,616 floats
// u16 region
constexpr size_t S_BASE = 2 * F_END;
constexpr size_t S_Y    = S_BASE;                    // [RP][512]  Y; later CTX
constexpr size_t S_V    = S_Y  + (size_t)RP*512;     // [RP][512]  V; HB starts here
constexpr size_t S_KF   = S_V  + (size_t)RP*512;     // [RP][1024] KF
constexpr size_t S_QF   = S_KF + (size_t)RP*1024;    // [RP][1024] QF
constexpr size_t S_WQKV = S_QF + (size_t)RP*1024;    // 1536*512
constexpr size_t S_WO   = S_WQKV + (size_t)1536*512; // 512*512
constexpr size_t S_WF1  = S_WO   + (size_t)512*512;  // 2048*512
constexpr size_t S_WF2  = S_WF1  + (size_t)2048*512; // 512*2048
constexpr size_t S_PT   = S_WF2  + (size_t)512*2048; // 8*128*64
constexpr size_t S_END  = S_PT   + (size_t)8*128*64;
constexpr size_t WS_BYTES = S_END * 2;               // 153,393,152

// ---------------- helpers ----------------
__device__ __forceinline__ float wave_reduce(float v) {
#pragma unroll
  for (int off = 32; off > 0; off >>= 1) v += __shfl_down(v, off, 64);
  return v;
}
__device__ __forceinline__ float b2f(u16 u) {
  union { float f; uint32_t i; } v; v.i = ((uint32_t)u) << 16; return v.f;
}
__device__ __forceinline__ u16 f2b(float f) {
  union { float f; uint32_t i; } v; v.f = f;
  uint32_t r = v.i + 0x7FFF + ((v.i >> 16) & 1);
  return (u16)(r >> 16);
}
__device__ __forceinline__ void gstage(const u16* g, u16* lds_base, int lane) {
#if __has_builtin(__builtin_amdgcn_global_load_lds)
  __builtin_amdgcn_global_load_lds((const __attribute__((address_space(1))) void*)g,
      (__attribute__((address_space(3))) void*)lds_base, 16, 0, 0);
#else
  *(u16x8*)(lds_base + lane * 8) = *(const u16x8*)g;
#endif
}
// XCD-aware bijective block swizzle (T1): contiguous work chunk per XCD.
// Requires nwg % 8 == 0 (all call sites satisfy; guarded anyway).
__device__ __forceinline__ void xcd_swz(int& bx, int& by) {
  int gx = gridDim.x;
  int nwg = gx * gridDim.y;
  int hw = blockIdx.x + blockIdx.y * gx;
  if (nwg & 7) { bx = blockIdx.x; by = blockIdx.y; return; }
  int cpx = nwg >> 3;
  int swz = (hw & 7) * cpx + (hw >> 3);
  bx = swz % gx; by = swz / gx;
}

// ---------------- embedding (grid RP: also zero-fills padding rows) -------
// NaN-hygiene: X padding rows (n in [NT,NP)) hard-zeroed so every
// downstream per-row op on padding rows stays finite; multiplicative
// masking is then exact (0 * finite == 0).
__global__ __launch_bounds__(256) void embed_k(const int* __restrict__ ids,
    const float* __restrict__ tok, const float* __restrict__ cls,
    const float* __restrict__ pos, float* __restrict__ X) {
  int row = blockIdx.x;
  int b = row / NP, n = row - b * NP;
  int t = threadIdx.x;
  size_t rp = (size_t)row;
  if (n >= NT) {
    X[rp * C_ + t]       = 0.f;
    X[rp * C_ + t + 256] = 0.f;
    return;
  }
  const float* src = (n == 0) ? cls : tok + (size_t)ids[b * N_ + n - 1] * C_;
  X[rp * C_ + t]       = src[t]       + pos[(size_t)n * C_ + t];
  X[rp * C_ + t + 256] = src[t + 256] + pos[(size_t)n * C_ + t + 256];
}

// ---------------- weight transpose + convert + PT + qkv bias (per layer) ----------------
__global__ __launch_bounds__(256) void wconv_k(
    const float* __restrict__ qW, const float* __restrict__ kW,
    const float* __restrict__ vW, const float* __restrict__ oW,
    const float* __restrict__ f1W, const float* __restrict__ f2W,
    const float* __restrict__ projL,
    const float* __restrict__ qb, const float* __restrict__ kb,
    const float* __restrict__ vb,
    u16* __restrict__ Wqkv, u16* __restrict__ Wo,
    u16* __restrict__ Wf1, u16* __restrict__ Wf2,
    u16* __restrict__ PT, float* __restrict__ QKVB) {
  __shared__ float tile[32][33];
  int bid = blockIdx.x, t = threadIdx.x;
  if (bid >= 3104) {            // qkv bias concat
    int i = (bid - 3104) * 256 + t;
    QKVB[i] = (i < 512) ? qb[i] : (i < 1024) ? kb[i - 512] : vb[i - 1024];
    return;
  }
  if (bid >= 3072) {            // PT[h][m][d] = proj[h][d][m]
    int base = (bid - 3072) * 2048 + t * 8;
#pragma unroll
    for (int j = 0; j < 8; ++j) {
      int idx = base + j;
      int h = idx >> 13, rem = idx & 8191, m = rem >> 6, d = rem & 63;
      PT[idx] = f2b(projL[(size_t)h * 8192 + d * 128 + m]);
    }
    return;
  }
  int ti = t >> 5, tj = t & 31;
  const float* src; u16* dst; int k0, n0, ldn, ldk, scol;
  if (bid < 768) {
    int tk = bid & 15, tn = bid >> 4;
    k0 = tk * 32; n0 = tn * 32;
    int sel = n0 >> 9; scol = n0 & 511;
    src = (sel == 0) ? qW : (sel == 1) ? kW : vW;
    ldn = 512; dst = Wqkv; ldk = 512;
  } else if (bid < 1024) {
    int b2 = bid - 768;
    int tk = b2 & 15, tn = b2 >> 4;
    k0 = tk * 32; n0 = tn * 32; scol = n0;
    src = oW; ldn = 512; dst = Wo; ldk = 512;
  } else if (bid < 2048) {
    int b2 = bid - 1024;
    int tk = b2 & 15, tn = b2 >> 4;
    k0 = tk * 32; n0 = tn * 32; scol = n0;
    src = f1W; ldn = 2048; dst = Wf1; ldk = 512;
  } else {
    int b2 = bid - 2048;
    int tk = b2 & 63, tn = b2 >> 6;
    k0 = tk * 32; n0 = tn * 32; scol = n0;
    src = f2W; ldn = 512; dst = Wf2; ldk = 2048;
  }
  const float* sp = src + (size_t)k0 * ldn + scol;
  u16* dp = dst + (size_t)n0 * ldk + k0;
#pragma unroll
  for (int p = 0; p < 4; ++p)
    tile[ti + p * 8][tj] = sp[(size_t)(ti + p * 8) * ldn + tj];
  __syncthreads();
#pragma unroll
  for (int p = 0; p < 4; ++p)
    dp[(size_t)(ti + p * 8) * ldk + tj] = f2b(tile[tj][ti + p * 8]);
}

// ---------------- LayerNorm -> bf16 ----------------
__global__ __launch_bounds__(256) void ln_bf_k(const float* __restrict__ X,
    const float* __restrict__ g, const float* __restrict__ b,
    u16* __restrict__ Y) {
  int w = threadIdx.x >> 6, lane = threadIdx.x & 63;
  int row = blockIdx.x * 4 + w;
  const float* xr = X + (size_t)row * C_;
  float v[8];
  *(float4*)&v[0] = *(const float4*)(xr + lane * 8);
  *(float4*)&v[4] = *(const float4*)(xr + lane * 8 + 4);
  float s = 0.f;
#pragma unroll
  for (int j = 0; j < 8; ++j) s += v[j];
  s = wave_reduce(s);
  float mu = __shfl(s, 0, 64) * (1.0f / C_);
  float sq = 0.f;
#pragma unroll
  for (int j = 0; j < 8; ++j) { float d = v[j] - mu; sq = fmaf(d, d, sq); }
  sq = wave_reduce(sq);
  float rs = rsqrtf(__shfl(sq, 0, 64) * (1.0f / C_) + LN_EPS_);
  float gv[8], bv[8];
  *(float4*)&gv[0] = *(const float4*)(g + lane * 8);
  *(float4*)&gv[4] = *(const float4*)(g + lane * 8 + 4);
  *(float4*)&bv[0] = *(const float4*)(b + lane * 8);
  *(float4*)&bv[4] = *(const float4*)(b + lane * 8 + 4);
  u16x8 o;
#pragma unroll
  for (int j = 0; j < 8; ++j) o[j] = f2b((v[j] - mu) * rs * gv[j] + bv[j]);
  *(u16x8*)(Y + (size_t)row * C_ + lane * 8) = o;
}

// ---------------- bf16 MFMA GEMM (fc1): BM=128, BK=64, 2-phase dbuf pipeline
// T3/T4-lite: double-buffered LDS, counted s_waitcnt vmcnt(8) (never 0 in
// steady state), raw s_barrier (no compiler vmcnt(0) drain). Next tile's 8
// DMA loads stay in flight across the barrier while MFMA runs.
// NOTE: round-4 measured the 256x256 8-phase port of this K=512 GEMM at
// 114.8us vs this kernel's 75.8us — short-K (8 K-tiles) + 520-block tail
// quantization defeat the deep pipeline. Keep this structure.
__global__ __launch_bounds__(256) void gemm_bf_k(
    const u16* __restrict__ A, int lda,
    const u16* __restrict__ Wt,
    const float* __restrict__ bias,
    float* __restrict__ outF, u16* __restrict__ outB,
    int ldc, int Kdim, int mode) {
  __shared__ __align__(16) u16 As[2][128 * 64];
  __shared__ __align__(16) u16 Bs[2][128 * 64];
  const int t = threadIdx.x, w = t >> 6, l = t & 63;
  int bx, by; xcd_swz(bx, by);
  const int row0 = by * 128, col0 = bx * 128;
  const int wm = w & 1, wn = w >> 1;
  const int lm = l & 15, lkb = l >> 4;
  const int lr = l >> 3, lc = l & 7;
  const int kch = (lc ^ lr) * 8;
  const u16* Ag = A  + (size_t)(row0 + lr) * lda  + kch;
  const u16* Bg = Wt + (size_t)(col0 + lr) * Kdim + kch;
  const int sx = lm & 7;
  f32x4 acc[4][4] = {};
  const int nk = Kdim >> 6;
  // prologue: stage tile 0 -> buffer 0
#pragma unroll
  for (int j = 0; j < 4; ++j) {
    int c8 = w * 4 + j;
    gstage(Ag + (size_t)c8 * 8 * lda , &As[0][c8 * 512], l);
    gstage(Bg + (size_t)c8 * 8 * Kdim, &Bs[0][c8 * 512], l);
  }
  for (int kt = 0; kt < nk; ++kt) {
    const int cur = kt & 1;
    if (kt + 1 < nk) {
      const int k0 = (kt + 1) << 6;
#pragma unroll
      for (int j = 0; j < 4; ++j) {
        int c8 = w * 4 + j;
        gstage(Ag + (size_t)c8 * 8 * lda  + k0, &As[cur ^ 1][c8 * 512], l);
        gstage(Bg + (size_t)c8 * 8 * Kdim + k0, &Bs[cur ^ 1][c8 * 512], l);
      }
      asm volatile("s_waitcnt vmcnt(8)" ::: "memory");  // tile kt landed; kt+1 in flight
    } else {
      asm volatile("s_waitcnt vmcnt(0)" ::: "memory");
    }
    __builtin_amdgcn_s_barrier();
    __builtin_amdgcn_sched_barrier(0);
#pragma unroll
    for (int ks = 0; ks < 2; ++ks) {
      frag af[4], bf4[4];
#pragma unroll
      for (int i = 0; i < 4; ++i)
        af[i] = *(const frag*)&As[cur][(wm * 64 + i * 16 + lm) * 64 + (((ks * 4 + lkb) ^ sx) * 8)];
#pragma unroll
      for (int j = 0; j < 4; ++j)
        bf4[j] = *(const frag*)&Bs[cur][(wn * 64 + j * 16 + lm) * 64 + (((ks * 4 + lkb) ^ sx) * 8)];
#pragma unroll
      for (int i = 0; i < 4; ++i)
#pragma unroll
        for (int j = 0; j < 4; ++j)
          acc[i][j] = __builtin_amdgcn_mfma_f32_16x16x32_bf16(af[i], bf4[j], acc[i][j], 0, 0, 0);
    }
    __builtin_amdgcn_sched_barrier(0);
    __builtin_amdgcn_s_barrier();   // all waves done reading buf[cur] before restage
  }
#pragma unroll
  for (int i = 0; i < 4; ++i) {
#pragma unroll
    for (int r = 0; r < 4; ++r) {
      int grow = row0 + wm * 64 + i * 16 + lkb * 4 + r;
      if (mode == MODE_RESID) {
        float* orow = outF + (size_t)grow * ldc + col0;
#pragma unroll
        for (int j = 0; j < 4; ++j) {
          int gc = wn * 64 + j * 16 + lm;
          orow[gc] += acc[i][j][r] + bias[col0 + gc];
        }
      } else { // MODE_GELU (fast sigmoid form)
        u16* orow = outB + (size_t)grow * ldc + col0;
#pragma unroll
        for (int j = 0; j < 4; ++j) {
          int gc = wn * 64 + j * 16 + lm;
          float v = acc[i][j][r] + bias[col0 + gc];
          float u = v * (1.5957691216f + 0.0713548162f * v * v);
          v = v / (1.f + __expf(-u));
          orow[gc] = f2b(v);
        }
      }
    }
  }
}

// ---------------- bf16 MFMA GEMM, BM=64 variant (o-proj / fc2), 2-phase dbuf
__global__ __launch_bounds__(256) void gemm_bf64_k(
    const u16* __restrict__ A, int lda,
    const u16* __restrict__ Wt,
    const float* __restrict__ bias,
    float* __restrict__ outF, u16* __restrict__ outB,
    int ldc, int Kdim, int mode) {
  __shared__ __align__(16) u16 As[2][64 * 64];
  __shared__ __align__(16) u16 Bs[2][128 * 64];
  const int t = threadIdx.x, w = t >> 6, l = t & 63;
  int bx, by; xcd_swz(bx, by);
  const int row0 = by * 64, col0 = bx * 128;
  const int wm = w & 1, wn = w >> 1;          // wave: 32 rows x 64 cols
  const int lm = l & 15, lkb = l >> 4;
  const int lr = l >> 3, lc = l & 7;
  const int kch = (lc ^ lr) * 8;
  const u16* Ag = A  + (size_t)(row0 + lr) * lda  + kch;
  const u16* Bg = Wt + (size_t)(col0 + lr) * Kdim + kch;
  const int sx = lm & 7;
  f32x4 acc[2][4] = {};
  const int nk = Kdim >> 6;
  // prologue: stage tile 0 -> buffer 0 (6 loads/wave: 2 A + 4 B)
#pragma unroll
  for (int q = 0; q < 2; ++q) {
    int c8 = w * 2 + q;
    gstage(Ag + (size_t)c8 * 8 * lda, &As[0][c8 * 512], l);
  }
#pragma unroll
  for (int q = 0; q < 4; ++q) {
    int c8 = w * 4 + q;
    gstage(Bg + (size_t)c8 * 8 * Kdim, &Bs[0][c8 * 512], l);
  }
  for (int kt = 0; kt < nk; ++kt) {
    const int cur = kt & 1;
    if (kt + 1 < nk) {
      const int k0 = (kt + 1) << 6;
#pragma unroll
      for (int q = 0; q < 2; ++q) {
        int c8 = w * 2 + q;
        gstage(Ag + (size_t)c8 * 8 * lda + k0, &As[cur ^ 1][c8 * 512], l);
      }
#pragma unroll
      for (int q = 0; q < 4; ++q) {
        int c8 = w * 4 + q;
        gstage(Bg + (size_t)c8 * 8 * Kdim + k0, &Bs[cur ^ 1][c8 * 512], l);
      }
      asm volatile("s_waitcnt vmcnt(6)" ::: "memory");
    } else {
      asm volatile("s_waitcnt vmcnt(0)" ::: "memory");
    }
    __builtin_amdgcn_s_barrier();
    __builtin_amdgcn_sched_barrier(0);
#pragma unroll
    for (int ks = 0; ks < 2; ++ks) {
      frag af[2], bf4[4];
#pragma unroll
      for (int i = 0; i < 2; ++i)
        af[i] = *(const frag*)&As[cur][(wm * 32 + i * 16 + lm) * 64 + (((ks * 4 + lkb) ^ sx) * 8)];
#pragma unroll
      for (int j = 0; j < 4; ++j)
        bf4[j] = *(const frag*)&Bs[cur][(wn * 64 + j * 16 + lm) * 64 + (((ks * 4 + lkb) ^ sx) * 8)];
#pragma unroll
      for (int i = 0; i < 2; ++i)
#pragma unroll
        for (int j = 0; j < 4; ++j)
          acc[i][j] = __builtin_amdgcn_mfma_f32_16x16x32_bf16(af[i], bf4[j], acc[i][j], 0, 0, 0);
    }
    __builtin_amdgcn_sched_barrier(0);
    __builtin_amdgcn_s_barrier();
  }
#pragma unroll
  for (int i = 0; i < 2; ++i) {
#pragma unroll
    for (int r = 0; r < 4; ++r) {
      int grow = row0 + wm * 32 + i * 16 + lkb * 4 + r;
      if (mode == MODE_RESID) {
        float* orow = outF + (size_t)grow * ldc + col0;
#pragma unroll
        for (int j = 0; j < 4; ++j) {
          int gc = wn * 64 + j * 16 + lm;
          orow[gc] += acc[i][j][r] + bias[col0 + gc];
        }
      } else { // MODE_GELU (fast sigmoid form)
        u16* orow = outB + (size_t)grow * ldc + col0;
#pragma unroll
        for (int j = 0; j < 4; ++j) {
          int gc = wn * 64 + j * 16 + lm;
          float v = acc[i][j][r] + bias[col0 + gc];
          float u = v * (1.5957691216f + 0.0713548162f * v * v);
          v = v / (1.f + __expf(-u));
          orow[gc] = f2b(v);
        }
      }
    }
  }
}

// ---------------- fused QKV GEMM + feature map ----------------
// grid (12, 130) swizzled. col-blocks 0..3: q-heads, 4..7: k-heads, 8..11: v.
// Masking is plain MULTIPLY: safe because embed_k zero-fills X padding
// (acc always finite). Round-7/8 A/B: compare+select cost 75->110us here.
__global__ __launch_bounds__(256) void gemmqkv_k(
    const u16* __restrict__ A,
    const u16* __restrict__ Wt,          // Wqkv [1536][512]
    const float* __restrict__ bias,      // [1536]
    u16* __restrict__ Vout,              // [RP][512]
    u16* __restrict__ QF, u16* __restrict__ KF,   // [RP][1024]
    const u16* __restrict__ PT,          // [8][128][64]
    const int* __restrict__ attn) {
  __shared__ __align__(16) u16 As[128 * 64];   // later: qtile head0
  __shared__ __align__(16) u16 Bs[128 * 64];   // later: qtile head1
  __shared__ __align__(16) u16 ptb[128 * 64];  // PT[h] staged, swizzled
  __shared__ float sxe[128][2];
  const int t = threadIdx.x, w = t >> 6, l = t & 63;
  int bx, by; xcd_swz(bx, by);
  const int cx = bx;
  const int row0 = by * 128, col0 = cx * 128;
  const int wm = w & 1, wn = w >> 1;
  const int lm = l & 15, lkb = l >> 4;
  const int lr = l >> 3, lc = l & 7;
  const int kch = (lc ^ lr) * 8;
  const u16* Ag = A  + (size_t)(row0 + lr) * 512 + kch;
  const u16* Bg = Wt + (size_t)(col0 + lr) * 512 + kch;
  const int sx = lm & 7;
  f32x4 acc[4][4] = {};
  for (int k0 = 0; k0 < 512; k0 += 64) {
    __syncthreads();
#pragma unroll
    for (int j = 0; j < 4; ++j) {
      int c8 = w * 4 + j;
      gstage(Ag + (size_t)c8 * 8 * 512 + k0, &As[c8 * 512], l);
      gstage(Bg + (size_t)c8 * 8 * 512 + k0, &Bs[c8 * 512], l);
    }
    __syncthreads();
#pragma unroll
    for (int ks = 0; ks < 2; ++ks) {
      frag af[4], bf4[4];
#pragma unroll
      for (int i = 0; i < 4; ++i)
        af[i] = *(const frag*)&As[(wm * 64 + i * 16 + lm) * 64 + (((ks * 4 + lkb) ^ sx) * 8)];
#pragma unroll
      for (int j = 0; j < 4; ++j)
        bf4[j] = *(const frag*)&Bs[(wn * 64 + j * 16 + lm) * 64 + (((ks * 4 + lkb) ^ sx) * 8)];
#pragma unroll
      for (int i = 0; i < 4; ++i)
#pragma unroll
        for (int j = 0; j < 4; ++j)
          acc[i][j] = __builtin_amdgcn_mfma_f32_16x16x32_bf16(af[i], bf4[j], acc[i][j], 0, 0, 0);
    }
  }
  // ---- V path ----
  if (cx >= 8) {
    int c0v = col0 - 1024;
#pragma unroll
    for (int i = 0; i < 4; ++i) {
#pragma unroll
      for (int r = 0; r < 4; ++r) {
        int grow = row0 + wm * 64 + i * 16 + lkb * 4 + r;
        int bb = grow / NP, nn = grow - bb * NP;
        float mrow = (nn == 0) ? 1.f : ((nn < NT) ? (float)attn[bb * N_ + nn - 1] : 0.f);
        u16* orow = Vout + (size_t)grow * 512 + c0v;
#pragma unroll
        for (int j = 0; j < 4; ++j) {
          int gc = wn * 64 + j * 16 + lm;
          orow[gc] = f2b((acc[i][j][r] + bias[col0 + gc]) * mrow);
        }
      }
    }
    return;
  }
  // ---- Q/K path: write scaled/masked tile to LDS (swizzled, per-head) ----
  const bool isq = (cx < 4);
  const int hbase = (isq ? cx : cx - 4) * 2;
  __syncthreads();            // all waves done reading As/Bs
  {
    u16* qt = wn ? Bs : As;
#pragma unroll
    for (int i = 0; i < 4; ++i) {
#pragma unroll
      for (int r = 0; r < 4; ++r) {
        int rl = wm * 64 + i * 16 + lkb * 4 + r;
        float mrow;
        if (isq) mrow = SCALE_;
        else {
          int grow = row0 + rl;
          int bb = grow / NP, nn = grow - bb * NP;
          mrow = (nn == 0) ? 1.f : ((nn < NT) ? (float)attn[bb * N_ + nn - 1] : 0.f);
        }
#pragma unroll
        for (int j = 0; j < 4; ++j) {
          int gcc = j * 16 + lm;
          float v = (acc[i][j][r] + bias[col0 + wn * 64 + gcc]) * mrow;
          qt[rl * 64 + (((gcc >> 3) ^ (rl & 7)) * 8) + (gcc & 7)] = f2b(v);
        }
      }
    }
  }
  // stage PT for head hbase+0 (independent of qtile)
  {
    const u16* Pg = PT + (size_t)hbase * 8192 + (size_t)lr * 64 + kch;
#pragma unroll
    for (int q = 0; q < 4; ++q) {
      int c8 = w * 4 + q;
      gstage(Pg + (size_t)c8 * 8 * 64, &ptb[c8 * 512], l);
    }
  }
  __syncthreads();
  // ---- 0.5*||x||^2 per (row, head) ----
  {
    int rowi = t >> 1, hf = t & 1;
    const u16* qq = hf ? Bs : As;
    float s = 0.f;
#pragma unroll
    for (int c = 0; c < 8; ++c) {
      const u16* p = &qq[rowi * 64 + ((c ^ (rowi & 7)) * 8)];
#pragma unroll
      for (int e = 0; e < 8; ++e) { float a = b2f(p[e]); s = fmaf(a, a, s); }
    }
    sxe[rowi][hf] = 0.5f * s;
  }
  __syncthreads();
  // ---- feature MFMA per head ----
  u16* OF = isq ? QF : KF;
#pragma unroll
  for (int hp = 0; hp < 2; ++hp) {
    if (hp == 1) {
      __syncthreads();
      const u16* Pg = PT + (size_t)(hbase + 1) * 8192 + (size_t)lr * 64 + kch;
#pragma unroll
      for (int q = 0; q < 4; ++q) {
        int c8 = w * 4 + q;
        gstage(Pg + (size_t)c8 * 8 * 64, &ptb[c8 * 512], l);
      }
      __syncthreads();
    }
    const u16* qt = hp ? Bs : As;
    f32x4 a2[2][8] = {};
#pragma unroll
    for (int ks = 0; ks < 2; ++ks) {
      frag af2[2], bf2[8];
#pragma unroll
      for (int i = 0; i < 2; ++i)
        af2[i] = *(const frag*)&qt[(w * 32 + i * 16 + lm) * 64 + (((ks * 4 + lkb) ^ sx) * 8)];
#pragma unroll
      for (int j = 0; j < 8; ++j)
        bf2[j] = *(const frag*)&ptb[(j * 16 + lm) * 64 + (((ks * 4 + lkb) ^ sx) * 8)];
#pragma unroll
      for (int i = 0; i < 2; ++i)
#pragma unroll
        for (int j = 0; j < 8; ++j)
          a2[i][j] = __builtin_amdgcn_mfma_f32_16x16x32_bf16(af2[i], bf2[j], a2[i][j], 0, 0, 0);
    }
    int hg = hbase + hp;
#pragma unroll
    for (int i = 0; i < 2; ++i) {
#pragma unroll
      for (int r = 0; r < 4; ++r) {
        int R = w * 32 + i * 16 + lkb * 4 + r;
        int grow = row0 + R;
        int bb = grow / NP, nn = grow - bb * NP;
        bool valid = nn < NT;
        float xs = sxe[R][hp];
        u16* orow = OF + (size_t)grow * 1024 + (size_t)hg * 128;
#pragma unroll
        for (int j = 0; j < 8; ++j) {
          int m = j * 16 + lm;
          float v = valid ? (__expf(a2[i][j][r] - xs) + FEAT_EPS_) : 0.f;
          orow[m] = f2b(v);
        }
      }
    }
  }
}

// ---------------- kv partial (pure accumulation, fp32) ----------------
// Round-3 form (4-way ci split): the round-4 8-way split doubled KVP
// partial HBM traffic and measured net-negative (round-8 A/B).
// Vectorized staging (u16x8) + register prefetch of next tile.
__global__ __launch_bounds__(256) void kvpart_k(const u16* __restrict__ KF,
    const u16* __restrict__ Vb, float* __restrict__ KVP,
    float* __restrict__ KSP) {
  int ci = blockIdx.x, bh = blockIdx.y;
  int b = bh >> 3, h = bh & 7;
  size_t rb0 = (size_t)b * NP + ci * 520;
  __shared__ __align__(16) float kfs[8 * 132];
  __shared__ __align__(16) float vsm[8 * 68];
  int t = threadIdx.x;
  const int d0 = (t & 7) * 8, m0 = (t >> 3) * 4;
  const bool hk = t < 128;
  const bool hv = (t >= 128) && (t < 192);
  const int ktok = t >> 4, kmj = (t & 15) * 8;
  const int vtok = (t - 128) >> 3, vdj = (t & 7) * 8;
  float acc[4][8] = {};
  float ks[4] = {};
  u16x8 rk, rv;
  if (hk) rk = *(const u16x8*)&KF[(rb0 + ktok) * 1024 + h * 128 + kmj];
  if (hv) rv = *(const u16x8*)&Vb[(rb0 + vtok) * 512 + h * 64 + vdj];
  for (int tile = 0; tile < 65; ++tile) {
    if (hk) {
#pragma unroll
      for (int e = 0; e < 8; ++e) kfs[ktok * 132 + kmj + e] = b2f(rk[e]);
    }
    if (hv) {
#pragma unroll
      for (int e = 0; e < 8; ++e) vsm[vtok * 68 + vdj + e] = b2f(rv[e]);
    }
    __syncthreads();
    if (tile + 1 < 65) {       // prefetch next tile into registers
      size_t rb = rb0 + (size_t)(tile + 1) * 8;
      if (hk) rk = *(const u16x8*)&KF[(rb + ktok) * 1024 + h * 128 + kmj];
      if (hv) rv = *(const u16x8*)&Vb[(rb + vtok) * 512 + h * 64 + vdj];
    }
#pragma unroll
    for (int tok = 0; tok < 8; ++tok) {
      float kq[4], va[8];
      *(float4*)&kq[0] = *(const float4*)&kfs[tok * 132 + m0];
      *(float4*)&va[0] = *(const float4*)&vsm[tok * 68 + d0];
      *(float4*)&va[4] = *(const float4*)&vsm[tok * 68 + d0 + 4];
#pragma unroll
      for (int mi = 0; mi < 4; ++mi)
#pragma unroll
        for (int di = 0; di < 8; ++di)
          acc[mi][di] = fmaf(kq[mi], va[di], acc[mi][di]);
      if ((t & 7) == 0) { ks[0] += kq[0]; ks[1] += kq[1]; ks[2] += kq[2]; ks[3] += kq[3]; }
    }
    __syncthreads();
  }
  size_t base = ((size_t)ci * 64 + bh) * 8192;
#pragma unroll
  for (int mi = 0; mi < 4; ++mi)
#pragma unroll
    for (int di = 0; di < 8; ++di)
      KVP[base + (size_t)(m0 + mi) * 64 + d0 + di] = acc[mi][di];
  if ((t & 7) == 0) {
#pragma unroll
    for (int mi = 0; mi < 4; ++mi)
      KSP[((size_t)ci * 64 + bh) * 128 + m0 + mi] = ks[mi];
  }
}

__global__ __launch_bounds__(256) void kvred_k(const float* __restrict__ KVP,
    const float* __restrict__ KSP, float* __restrict__ KV,
    float* __restrict__ KSUM) {
  int bh = blockIdx.x, t = threadIdx.x;
#pragma unroll
  for (int p = 0; p < 32; ++p) {
    int e = p * 256 + t;
    float s = 0.f;
#pragma unroll
    for (int ci = 0; ci < 4; ++ci) s += KVP[((size_t)ci * 64 + bh) * 8192 + e];
    KV[(size_t)bh * 8192 + e] = s;
  }
  if (t < 128) {
    float s = 0.f;
#pragma unroll
    for (int ci = 0; ci < 4; ++ci) s += KSP[((size_t)ci * 64 + bh) * 128 + t];
    KSUM[(size_t)bh * 128 + t] = s;
  }
}

// ---------------- ctx: (qf @ kv) / max(qf . ksum, 1e-6) ----------------
// Round-3 form ([m][36] qfs layout — conflict-free denominator; the
// round-4 [tok][132] transpose measured net-negative in round-8 A/B).
// Padding rows written as zero (NaN/stale hygiene; same store count).
__global__ __launch_bounds__(256) void ctx_k(const u16* __restrict__ QF,
    const float* __restrict__ KVg, const float* __restrict__ KSUM,
    u16* __restrict__ CTXo) {
  __shared__ float qfs[128 * 36];
  __shared__ float kvs[128 * 68];
  __shared__ float ksums[128];
  __shared__ float dls[32];
  __shared__ float dpart[8 * 32];
  int t = threadIdx.x;
  int bx, by; xcd_swz(bx, by);
  int bh = by; int b = bh >> 3, h = bh & 7;
  int n0 = bx * 32;
  size_t rbase = (size_t)b * NP + n0;
#pragma unroll
  for (int p = 0; p < 16; ++p) {
    int e = p * 256 + t; int m = e & 127; int tok = e >> 7;
    qfs[m * 36 + tok] = b2f(QF[(rbase + tok) * 1024 + h * 128 + m]);
  }
#pragma unroll
  for (int p = 0; p < 32; ++p) {
    int e = p * 256 + t;
    kvs[(e >> 6) * 68 + (e & 63)] = KVg[(size_t)bh * 8192 + e];
  }
  if (t < 128) ksums[t] = KSUM[bh * 128 + t];
  __syncthreads();
  {
    int j = t & 31, pp = t >> 5;
    float s = 0.f;
#pragma unroll
    for (int mi = 0; mi < 16; ++mi) {
      int m = pp * 16 + mi;
      s = fmaf(qfs[m * 36 + j], ksums[m], s);
    }
    dpart[pp * 32 + j] = s;
  }
  __syncthreads();
  if (t < 32) {
    float den = 0.f;
#pragma unroll
    for (int pp = 0; pp < 8; ++pp) den += dpart[pp * 32 + t];
    dls[t] = 1.f / fmaxf(den, 1e-6f);
  }
  __syncthreads();
  {
    const int d0 = (t & 15) * 4, tok0 = (t >> 4) * 2;
    float acc[2][4] = {};
#pragma unroll 16
    for (int m = 0; m < 128; ++m) {
      float q0 = qfs[m * 36 + tok0];
      float q1 = qfs[m * 36 + tok0 + 1];
      float4 kv4 = *(const float4*)&kvs[m * 68 + d0];
      acc[0][0] = fmaf(q0, kv4.x, acc[0][0]); acc[0][1] = fmaf(q0, kv4.y, acc[0][1]);
      acc[0][2] = fmaf(q0, kv4.z, acc[0][2]); acc[0][3] = fmaf(q0, kv4.w, acc[0][3]);
      acc[1][0] = fmaf(q1, kv4.x, acc[1][0]); acc[1][1] = fmaf(q1, kv4.y, acc[1][1]);
      acc[1][2] = fmaf(q1, kv4.z, acc[1][2]); acc[1][3] = fmaf(q1, kv4.w, acc[1][3]);
    }
#pragma unroll
    for (int r = 0; r < 2; ++r) {
      int n = n0 + tok0 + r;
      bool pad = (n >= NT);
      float rd = pad ? 0.f : dls[tok0 + r];
      u16* o = CTXo + (rbase + tok0 + r) * C_ + h * HD_ + d0;
#pragma unroll
      for (int c = 0; c < 4; ++c) o[c] = f2b(pad ? 0.f : acc[r][c] * rd);
    }
  }
}

// ---------------- final: LN(x[b,0]) @ headW + headb ----------------
__global__ __launch_bounds__(256) void final_k(const float* __restrict__ X,
    const float* __restrict__ g, const float* __restrict__ beta,
    const float* __restrict__ hW, const float* __restrict__ hb,
    float* __restrict__ out) {
  int b = blockIdx.x, t = threadIdx.x;
  const float* xr = X + (size_t)b * NP * C_;
  float v0 = xr[t], v1 = xr[t + 256];
  __shared__ float red[4][4];
  float s = wave_reduce(v0 + v1);
  if ((t & 63) == 0) red[0][t >> 6] = s;
  __syncthreads();
  float mu = (red[0][0] + red[0][1] + red[0][2] + red[0][3]) * (1.0f / C_);
  float d0 = v0 - mu, d1 = v1 - mu;
  float s2 = wave_reduce(d0 * d0 + d1 * d1);
  if ((t & 63) == 0) red[1][t >> 6] = s2;
  __syncthreads();
  float var = (red[1][0] + red[1][1] + red[1][2] + red[1][3]) * (1.0f / C_);
  float rs = rsqrtf(var + LN_EPS_);
  float n0 = d0 * rs * g[t] + beta[t];
  float n1 = d1 * rs * g[t + 256] + beta[t + 256];
  float p0 = n0 * hW[t * NC_]     + n1 * hW[(t + 256) * NC_];
  float p1 = n0 * hW[t * NC_ + 1] + n1 * hW[(t + 256) * NC_ + 1];
  float t0 = wave_reduce(p0);
  float t1 = wave_reduce(p1);
  if ((t & 63) == 0) { red[2][t >> 6] = t0; red[3][t >> 6] = t1; }
  __syncthreads();
  if (t == 0) {
    out[b * NC_]     = red[2][0] + red[2][1] + red[2][2] + red[2][3] + hb[0];
    out[b * NC_ + 1] = red[3][0] + red[3][1] + red[3][2] + red[3][3] + hb[1];
  }
}

// ---------------- launch ----------------
extern "C" void kernel_launch(void* const* d_in, const int* in_sizes, int n_in,
                              void* d_out, int out_size, void* d_ws, size_t ws_size,
                              hipStream_t stream) {
  if (ws_size < WS_BYTES) return;  // diagnostic guard
  const int*   ids   = (const int*)d_in[0];
  const int*   attn  = (const int*)d_in[1];
  const float* tok   = (const float*)d_in[2];
  const float* cls   = (const float*)d_in[3];
  const float* pos   = (const float*)d_in[4];
  const float* ln1g  = (const float*)d_in[5];
  const float* ln1b  = (const float*)d_in[6];
  const float* qW    = (const float*)d_in[7];
  const float* qb    = (const float*)d_in[8];
  const float* kW    = (const float*)d_in[9];
  const float* kb    = (const float*)d_in[10];
  const float* vW    = (const float*)d_in[11];
  const float* vb    = (const float*)d_in[12];
  const float* oW    = (const float*)d_in[13];
  const float* ob    = (const float*)d_in[14];
  const float* proj  = (const float*)d_in[15];
  const float* ln2g  = (const float*)d_in[16];
  const float* ln2b  = (const float*)d_in[17];
  const float* fc1W  = (const float*)d_in[18];
  const float* fc1b  = (const float*)d_in[19];
  const float* fc2W  = (const float*)d_in[20];
  const float* fc2b  = (const float*)d_in[21];
  const float* lnfg  = (const float*)d_in[22];
  const float* lnfb  = (const float*)d_in[23];
  const float* headW = (const float*)d_in[24];
  const float* headb = (const float*)d_in[25];

  float* ws  = (float*)d_ws;
  u16*   wsu = (u16*)d_ws;
  float* X    = ws + F_X;
  float* KVP  = ws + F_KVP;
  float* KSP  = ws + F_KSP;
  float* KV   = ws + F_KV;
  float* KSUM = ws + F_KS;
  float* QKVB = ws + F_QKVB;
  u16* Ybf  = wsu + S_Y;    // [RP][512]; CTX aliases (temporally disjoint)
  u16* CTXb = wsu + S_Y;
  u16* Vb   = wsu + S_V;    // [RP][512]; HB[RP][2048] starts here (V+KF+QF/2 dead by FFN)
  u16* HB   = wsu + S_V;
  u16* KFb  = wsu + S_KF;   // [RP][1024]
  u16* QFb  = wsu + S_QF;   // [RP][1024]
  u16* Wqkv = wsu + S_WQKV;
  u16* Wo   = wsu + S_WO;
  u16* Wf1  = wsu + S_WF1;
  u16* Wf2  = wsu + S_WF2;
  u16* PT   = wsu + S_PT;

  embed_k<<<RP, 256, 0, stream>>>(ids, tok, cls, pos, X);
  for (int i = 0; i < L_; ++i) {
    wconv_k<<<3110, 256, 0, stream>>>(qW + (size_t)i * C_ * C_, kW + (size_t)i * C_ * C_,
        vW + (size_t)i * C_ * C_, oW + (size_t)i * C_ * C_,
        fc1W + (size_t)i * C_ * HID_, fc2W + (size_t)i * HID_ * C_,
        proj + (size_t)i * H_ * HD_ * M_,
        qb + i * C_, kb + i * C_, vb + i * C_,
        Wqkv, Wo, Wf1, Wf2, PT, QKVB);
    ln_bf_k<<<RP / 4, 256, 0, stream>>>(X, ln1g + i * C_, ln1b + i * C_, Ybf);
    gemmqkv_k<<<dim3(12, 130), 256, 0, stream>>>(Ybf, Wqkv, QKVB,
        Vb, QFb, KFb, PT, attn);
    kvpart_k<<<dim3(4, 64), 256, 0, stream>>>(KFb, Vb, KVP, KSP);
    kvred_k<<<64, 256, 0, stream>>>(KVP, KSP, KV, KSUM);
    ctx_k<<<dim3(65, 64), 256, 0, stream>>>(QFb, KV, KSUM, CTXb);
    gemm_bf64_k<<<dim3(4, 260), 256, 0, stream>>>(CTXb, 512, Wo, ob + i * C_,
        X, nullptr, 512, 512, MODE_RESID);
    ln_bf_k<<<RP / 4, 256, 0, stream>>>(X, ln2g + i * C_, ln2b + i * C_, Ybf);
    gemm_bf_k<<<dim3(16, 130), 256, 0, stream>>>(Ybf, 512, Wf1,
        fc1b + i * HID_, nullptr, HB, 2048, 512, MODE_GELU);
    gemm_bf64_k<<<dim3(4, 260), 256, 0, stream>>>(HB, 2048, Wf2,
        fc2b + i * C_, X, nullptr, 512, 2048, MODE_RESID);
  }
  final_k<<<B_, 256, 0, stream>>>(X, lnfg, lnfb, headW, headb, (float*)d_out);
}